// Round 31
// baseline (135.766 us; speedup 1.0000x reference)
//
#include <hip/hip_runtime.h>
#include <math.h>

#define NH 16
#define HD 64
#define DMODEL 1024
#define NSEQ 2048
#define BATCH 2
#define CHUNK 32
#define NCH (NSEQ / CHUNK)            // 64 chunks
#define LN_BASE 9.210340371976184f    // ln(10000)

typedef __attribute__((ext_vector_type(8))) short bf16x8;
typedef __attribute__((ext_vector_type(8))) unsigned short u16x8;
typedef __attribute__((ext_vector_type(4))) float f32x4;

__device__ __forceinline__ unsigned short f2bf(float f) {
  union { float f; unsigned int u; } v; v.f = f;
  unsigned int u = v.u;
  unsigned int r = u + 0x7FFFu + ((u >> 16) & 1u);   // RNE
  return (unsigned short)(r >> 16);
}
__device__ __forceinline__ float bf2f(unsigned short u) {
  union { unsigned int u; float f; } v; v.u = ((unsigned int)u) << 16;
  return v.f;
}

// Fast range-reduced sincos (HW v_sin/v_cos after reduction to one revolution).
__device__ __forceinline__ void fast_sincos(float ang, float* s, float* c) {
  const float INV2PI = 0.15915494309189535f;
  const float TWOPI  = 6.283185307179586f;
  float rev = ang * INV2PI;
  rev = rev - floorf(rev);          // [0,1)
  float ar = rev * TWOPI;
  *s = __sinf(ar);
  *c = __cosf(ar);
}

// Async global->LDS, 16B per lane (dest = wave-uniform base + lane*16).
__device__ __forceinline__ void gload_lds16(const unsigned short* g,
                                            unsigned short* l) {
  __builtin_amdgcn_global_load_lds(
      (const __attribute__((address_space(1))) void*)g,
      (__attribute__((address_space(3))) void*)l, 16, 0, 0);
}

// ---------------------------------------------------------------------------
// Batched transposes + x conversion (round-31):
//   z=0..3 : [1024][1024] f32 -> bf16^T   (wq wk wv wo)
//   z=4    : x f32 -> bf16 linear
//   z=5    : wg1 [1024][64]  -> wg1T [64][1024]  (only blockIdx.x<2 active)
//   z=6    : wg2 [64][1024]  -> wg2T [1024][64]  (only blockIdx.y<2 active)
// ---------------------------------------------------------------------------
__global__ __launch_bounds__(256) void transpose_cvt7(
    const float* __restrict__ s0, const float* __restrict__ s1,
    const float* __restrict__ s2, const float* __restrict__ s3,
    const float* __restrict__ xs, const float* __restrict__ wg1,
    const float* __restrict__ wg2,
    unsigned short* __restrict__ d0, unsigned short* __restrict__ d1,
    unsigned short* __restrict__ d2, unsigned short* __restrict__ d3,
    unsigned short* __restrict__ xd, unsigned short* __restrict__ wg1T,
    unsigned short* __restrict__ wg2T) {
  const int z = blockIdx.z;
  if (z == 4) {
    const int lin = blockIdx.y * 32 + blockIdx.x;   // 0..1023
    const size_t base = (size_t)lin * 4096 + threadIdx.x * 4;
#pragma unroll
    for (int r = 0; r < 4; ++r) {
      float4 v = *(const float4*)(xs + base + r * 1024);
      unsigned short* o = xd + base + r * 1024;
      o[0] = f2bf(v.x); o[1] = f2bf(v.y); o[2] = f2bf(v.z); o[3] = f2bf(v.w);
    }
    return;
  }
  const float* in;
  unsigned short* out;
  int R, Cn;
  if (z < 4) {
    in = (z == 0) ? s0 : (z == 1) ? s1 : (z == 2) ? s2 : s3;
    out = (z == 0) ? d0 : (z == 1) ? d1 : (z == 2) ? d2 : d3;
    R = DMODEL; Cn = DMODEL;
  } else if (z == 5) {
    if (blockIdx.x >= 2) return;     // Cn=64 -> 2 col-tiles
    in = wg1; out = wg1T; R = DMODEL; Cn = 64;
  } else {
    if (blockIdx.y >= 2) return;     // R=64 -> 2 row-tiles
    in = wg2; out = wg2T; R = 64; Cn = DMODEL;
  }
  __shared__ float tl[32][33];
  const int t = threadIdx.x;
  const int ci = t & 31, ri = t >> 5;   // ri in 0..7
  const int br = blockIdx.y * 32, bc = blockIdx.x * 32;
#pragma unroll
  for (int rr = 0; rr < 4; ++rr)
    tl[ri + rr * 8][ci] = in[(size_t)(br + ri + rr * 8) * Cn + bc + ci];
  __syncthreads();
#pragma unroll
  for (int rr = 0; rr < 4; ++rr) {
    const int orow = bc + ri + rr * 8;   // output row = input col
    const int ocol = br + ci;            // output col = input row
    out[(size_t)orow * R + ocol] = f2bf(tl[ci][ri + rr * 8]);
  }
}

// ---------------------------------------------------------------------------
// g1 = x[4096][1024] @ wg1T[64][1024]^T -> bf16 [4096][64]  (round-31:
// low-rank gate step 1).  BM=16, N=64, BK=64 -> 256 blocks (1/CU).
// 4 waves: waves 0-1 stage A (8 rows each), all stage B (16 rows each);
// wave w computes the 16x16 n-tile w.  Same XOR-swizzle staging template.
// ---------------------------------------------------------------------------
__global__ __launch_bounds__(256) void gemm_bf16_g1(
    const unsigned short* __restrict__ A, const unsigned short* __restrict__ Bt,
    unsigned short* __restrict__ C) {
  __shared__ unsigned short As[16][64];    // 2 KB
  __shared__ unsigned short Bs[64][64];    // 8 KB
  const int tid = threadIdx.x;
  const int l = tid & 63;
  const int w = tid >> 6;
  const int bm = blockIdx.x * 16;
  const int K = DMODEL;

  const int lrow = l >> 3;
  const int cd = l & 7;
  const int cl = cd ^ lrow;

  f32x4 acc = (f32x4){0.f, 0.f, 0.f, 0.f};

  for (int k0 = 0; k0 < K; k0 += 64) {
    __syncthreads();
    if (w < 2) {                        // A: wave w stages rows [w*8, w*8+8)
      const int row = w * 8 + lrow;
      unsigned short* la = (unsigned short*)As + (w * 8) * 64 + l * 8;
      gload_lds16(A + (size_t)(bm + row) * K + k0 + cl * 8, la);
    }
    {                                   // B: wave w stages rows [w*16, w*16+16)
#pragma unroll
      for (int c = 0; c < 2; ++c) {
        const int row = w * 16 + c * 8 + lrow;
        unsigned short* lb = (unsigned short*)Bs + (w * 16 + c * 8) * 64 + l * 8;
        gload_lds16(Bt + (size_t)row * K + k0 + cl * 8, lb);
      }
    }
    __syncthreads();

#pragma unroll
    for (int ks = 0; ks < 2; ++ks) {
      bf16x8 af, bfr;
      {
        const int r = l & 15;
        const int phys = (ks * 4 + (l >> 4)) ^ (r & 7);
        af = *(const bf16x8*)&As[r][phys * 8];
      }
      {
        const int r = w * 16 + (l & 15);
        const int phys = (ks * 4 + (l >> 4)) ^ (r & 7);
        bfr = *(const bf16x8*)&Bs[r][phys * 8];
      }
      acc = __builtin_amdgcn_mfma_f32_16x16x32_bf16(af, bfr, acc, 0, 0, 0);
    }
  }

  {
    const int row0 = bm + (l >> 4) * 4;
    const int col = w * 16 + (l & 15);
#pragma unroll
    for (int r = 0; r < 4; ++r)
      C[(size_t)(row0 + r) * 64 + col] = f2bf(acc[r]);
  }
}

// ---------------------------------------------------------------------------
// gate = g1[4096][64] @ wg2T[1024][64]^T -> bf16 (round-31: low-rank gate
// step 2; clone of verified wo structure, K=64 single tile, bf16 out).
// BM=32, BN=128 -> 1024 blocks (4/CU).
// ---------------------------------------------------------------------------
__global__ __launch_bounds__(256, 6) void gemm_bf16_gate(
    const unsigned short* __restrict__ A, const unsigned short* __restrict__ Bt,
    unsigned short* __restrict__ C, int M, int N, int K) {
  __shared__ unsigned short As[32][64];    // 4 KB
  __shared__ unsigned short Bs[128][64];   // 16 KB
  const int tid = threadIdx.x;
  const int l = tid & 63;
  const int w = tid >> 6;
  const int wr = (w >> 1) * 16;            // 0/16
  const int wc = (w & 1) * 64;

  const int nwg = gridDim.x;               // 1024
  const int orig = blockIdx.x;
  const int swz = (orig & 7) * (nwg >> 3) + (orig >> 3);
  const int ntn = N >> 7;                  // 8
  const int bm = (swz / ntn) * 32;
  const int bn = (swz % ntn) * 128;

  const int lrow = l >> 3;
  const int cd = l & 7;
  const int cl = cd ^ lrow;

  f32x4 acc[4];
#pragma unroll
  for (int n = 0; n < 4; ++n) acc[n] = (f32x4){0.f, 0.f, 0.f, 0.f};

  for (int k0 = 0; k0 < K; k0 += 64) {
    __syncthreads();
    {                                   // A: wave stages rows [w*8, w*8+8)
      const int row = w * 8 + lrow;
      unsigned short* la = (unsigned short*)As + (w * 8) * 64 + l * 8;
      gload_lds16(A + (size_t)(bm + row) * K + k0 + cl * 8, la);
    }
#pragma unroll
    for (int c = 0; c < 4; ++c) {       // B: wave stages rows [w*32, w*32+32)
      const int row = w * 32 + c * 8 + lrow;
      unsigned short* lb = (unsigned short*)Bs + (w * 32 + c * 8) * 64 + l * 8;
      gload_lds16(Bt + (size_t)(bn + row) * K + k0 + cl * 8, lb);
    }
    __syncthreads();

#pragma unroll
    for (int ks = 0; ks < 2; ++ks) {
      bf16x8 af, bfr[4];
      {
        const int r = wr + (l & 15);
        const int phys = (ks * 4 + (l >> 4)) ^ (r & 7);
        af = *(const bf16x8*)&As[r][phys * 8];
      }
#pragma unroll
      for (int n = 0; n < 4; ++n) {
        const int r = wc + n * 16 + (l & 15);
        const int phys = (ks * 4 + (l >> 4)) ^ (r & 7);
        bfr[n] = *(const bf16x8*)&Bs[r][phys * 8];
      }
#pragma unroll
      for (int n = 0; n < 4; ++n)
        acc[n] = __builtin_amdgcn_mfma_f32_16x16x32_bf16(af, bfr[n], acc[n], 0, 0, 0);
    }
  }

  {
    const int row0 = bm + wr + (l >> 4) * 4;
#pragma unroll
    for (int n = 0; n < 4; ++n) {
      const int col = bn + wc + n * 16 + (l & 15);
#pragma unroll
      for (int r = 0; r < 4; ++r)
        C[(size_t)(row0 + r) * N + col] = f2bf(acc[n][r]);
    }
  }
}

// ---------------------------------------------------------------------------
// bf16 MFMA GEMM, fused 3-output (round-31: gate band moved to low-rank
// path; Ntot=3072 -> 768 blocks = exactly 3 block-rounds).  BM=128 single
// buffer (round-28/30 verified optimum).  2D XCD regions: 768 = 8 XCD x 96;
// 32 bm x 24 bn tiles; region = 8 bm x 12 bn.  Bands -> B0..B2, silu on B0.
// ---------------------------------------------------------------------------
__global__ __launch_bounds__(256, 4) void gemm_bf16_fused(
    const unsigned short* __restrict__ A, const unsigned short* __restrict__ Bt,
    unsigned short* __restrict__ B0, unsigned short* __restrict__ B1,
    unsigned short* __restrict__ B2,
    int M, int Ntot, int K) {
  __shared__ unsigned short As[128][64];   // 16 KB
  __shared__ unsigned short Bs[128][64];   // 16 KB
  const int tid = threadIdx.x;
  const int l = tid & 63;
  const int w = tid >> 6;
  const int wr = (w >> 1) * 64;
  const int wc = (w & 1) * 64;

  const int orig = blockIdx.x;
  const int xcd = orig & 7;
  const int idx = orig >> 3;               // 0..95
  const int bm = ((xcd >> 1) * 8 + (idx & 7)) * 128;
  const int bn = ((xcd & 1) * 12 + (idx >> 3)) * 128;

  const int lrow = l >> 3;                 // 0..7 row within call
  const int cd = l & 7;                    // dest 16B chunk
  const int cl = cd ^ lrow;                // logical chunk fetched (row&7==lrow)

  f32x4 acc[4][4];
#pragma unroll
  for (int m = 0; m < 4; ++m)
#pragma unroll
    for (int n = 0; n < 4; ++n) acc[m][n] = (f32x4){0.f, 0.f, 0.f, 0.f};

  for (int k0 = 0; k0 < K; k0 += 64) {
    __syncthreads();   // previous iteration's ds_reads complete
#pragma unroll
    for (int c = 0; c < 4; ++c) {       // A: wave stages rows [w*32, w*32+32)
      const int row = w * 32 + c * 8 + lrow;
      unsigned short* la = (unsigned short*)As + (w * 32 + c * 8) * 64 + l * 8;
      gload_lds16(A + (size_t)(bm + row) * K + k0 + cl * 8, la);
    }
#pragma unroll
    for (int c = 0; c < 4; ++c) {       // B: wave stages rows [w*32, w*32+32)
      const int row = w * 32 + c * 8 + lrow;
      unsigned short* lb = (unsigned short*)Bs + (w * 32 + c * 8) * 64 + l * 8;
      gload_lds16(Bt + (size_t)(bn + row) * K + k0 + cl * 8, lb);
    }
    __syncthreads();   // vmcnt(0) drained before barrier -> tiles ready

#pragma unroll
    for (int ks = 0; ks < 2; ++ks) {
      bf16x8 af[4], bfr[4];
#pragma unroll
      for (int m = 0; m < 4; ++m) {
        const int r = wr + m * 16 + (l & 15);
        const int phys = (ks * 4 + (l >> 4)) ^ (r & 7);
        af[m] = *(const bf16x8*)&As[r][phys * 8];
      }
#pragma unroll
      for (int n = 0; n < 4; ++n) {
        const int r = wc + n * 16 + (l & 15);
        const int phys = (ks * 4 + (l >> 4)) ^ (r & 7);
        bfr[n] = *(const bf16x8*)&Bs[r][phys * 8];
      }
#pragma unroll
      for (int m = 0; m < 4; ++m)
#pragma unroll
        for (int n = 0; n < 4; ++n)
          acc[m][n] = __builtin_amdgcn_mfma_f32_16x16x32_bf16(af[m], bfr[n], acc[m][n], 0, 0, 0);
    }
  }

#pragma unroll
  for (int m = 0; m < 4; ++m) {
    const int row0 = bm + wr + m * 16 + (l >> 4) * 4;
#pragma unroll
    for (int n = 0; n < 4; ++n) {
      const int colw = wc + n * 16 + (l & 15);
#pragma unroll
      for (int r = 0; r < 4; ++r) {
        float x = acc[m][n][r];
        const int nb = bn >> 10;
        unsigned short* Bb = (nb == 0) ? B0 : (nb == 1) ? B1 : B2;
        const int col = (bn & 1023) + colw;
        if (nb == 0) x = x / (1.f + expf(-x));
        Bb[(size_t)(row0 + r) * DMODEL + col] = f2bf(x);
      }
    }
  }
}

// ---------------------------------------------------------------------------
// wo GEMM (round-26 verified: BM=32 -> 1024 blocks = 4/CU).  f32 output.
// ---------------------------------------------------------------------------
__global__ __launch_bounds__(256, 6) void gemm_bf16_wo(
    const unsigned short* __restrict__ A, const unsigned short* __restrict__ Bt,
    float* __restrict__ C, int M, int N, int K) {
  __shared__ unsigned short As[32][64];    // 4 KB
  __shared__ unsigned short Bs[128][64];   // 16 KB
  const int tid = threadIdx.x;
  const int l = tid & 63;
  const int w = tid >> 6;
  const int wr = (w >> 1) * 16;            // 0/16
  const int wc = (w & 1) * 64;

  const int nwg = gridDim.x;               // 1024
  const int orig = blockIdx.x;
  const int swz = (orig & 7) * (nwg >> 3) + (orig >> 3);
  const int ntn = N >> 7;                  // 8
  const int bm = (swz / ntn) * 32;
  const int bn = (swz % ntn) * 128;

  const int lrow = l >> 3;
  const int cd = l & 7;
  const int cl = cd ^ lrow;

  f32x4 acc[4];
#pragma unroll
  for (int n = 0; n < 4; ++n) acc[n] = (f32x4){0.f, 0.f, 0.f, 0.f};

  for (int k0 = 0; k0 < K; k0 += 64) {
    __syncthreads();
    {                                   // A: wave stages rows [w*8, w*8+8)
      const int row = w * 8 + lrow;
      unsigned short* la = (unsigned short*)As + (w * 8) * 64 + l * 8;
      gload_lds16(A + (size_t)(bm + row) * K + k0 + cl * 8, la);
    }
#pragma unroll
    for (int c = 0; c < 4; ++c) {       // B: wave stages rows [w*32, w*32+32)
      const int row = w * 32 + c * 8 + lrow;
      unsigned short* lb = (unsigned short*)Bs + (w * 32 + c * 8) * 64 + l * 8;
      gload_lds16(Bt + (size_t)(bn + row) * K + k0 + cl * 8, lb);
    }
    __syncthreads();

#pragma unroll
    for (int ks = 0; ks < 2; ++ks) {
      bf16x8 af, bfr[4];
      {
        const int r = wr + (l & 15);
        const int phys = (ks * 4 + (l >> 4)) ^ (r & 7);
        af = *(const bf16x8*)&As[r][phys * 8];
      }
#pragma unroll
      for (int n = 0; n < 4; ++n) {
        const int r = wc + n * 16 + (l & 15);
        const int phys = (ks * 4 + (l >> 4)) ^ (r & 7);
        bfr[n] = *(const bf16x8*)&Bs[r][phys * 8];
      }
#pragma unroll
      for (int n = 0; n < 4; ++n)
        acc[n] = __builtin_amdgcn_mfma_f32_16x16x32_bf16(af, bfr[n], acc[n], 0, 0, 0);
    }
  }

  {
    const int row0 = bm + wr + (l >> 4) * 4;
#pragma unroll
    for (int n = 0; n < 4; ++n) {
      const int col = bn + wc + n * 16 + (l & 15);
#pragma unroll
      for (int r = 0; r < 4; ++r)
        C[(size_t)(row0 + r) * N + col] = acc[n][r];
    }
  }
}

// ---------------------------------------------------------------------------
// Tiled fp32 GEMM (fallback path only).
// ---------------------------------------------------------------------------
template <int ACT>
__global__ __launch_bounds__(256) void gemm_f32(const float* __restrict__ A,
                                                const float* __restrict__ B,
                                                float* __restrict__ C,
                                                int M, int N, int K) {
  __shared__ __align__(16) float As[16][128];
  __shared__ __align__(16) float Bs[16][128];
  const int tid = threadIdx.x;
  const int tx = tid & 15;
  const int ty = tid >> 4;
  const int bm = blockIdx.y * 128;
  const int bn = blockIdx.x * 128;

  float acc[8][8];
#pragma unroll
  for (int i = 0; i < 8; ++i)
#pragma unroll
    for (int j = 0; j < 8; ++j) acc[i][j] = 0.f;

  for (int k0 = 0; k0 < K; k0 += 16) {
    {
      const int row = tid >> 1;
      const int ko = (tid & 1) * 8;
      const float* src = A + (size_t)(bm + row) * K + k0 + ko;
      float4 a0 = *(const float4*)src;
      float4 a1 = *(const float4*)(src + 4);
      As[ko + 0][row] = a0.x; As[ko + 1][row] = a0.y;
      As[ko + 2][row] = a0.z; As[ko + 3][row] = a0.w;
      As[ko + 4][row] = a1.x; As[ko + 5][row] = a1.y;
      As[ko + 6][row] = a1.z; As[ko + 7][row] = a1.w;
    }
    {
      const int kr = tid >> 4;
      const int no = (tid & 15) * 8;
      float4 b0 = make_float4(0.f, 0.f, 0.f, 0.f);
      float4 b1 = b0;
      if (no < N) {
        const float* src = B + (size_t)(k0 + kr) * N + bn + no;
        b0 = *(const float4*)src;
        b1 = *(const float4*)(src + 4);
      }
      *(float4*)&Bs[kr][no] = b0;
      *(float4*)&Bs[kr][no + 4] = b1;
    }
    __syncthreads();
#pragma unroll
    for (int kk = 0; kk < 16; ++kk) {
      float a[8], b[8];
      *(float4*)&a[0] = *(const float4*)&As[kk][ty * 8];
      *(float4*)&a[4] = *(const float4*)&As[kk][ty * 8 + 4];
      *(float4*)&b[0] = *(const float4*)&Bs[kk][tx * 8];
      *(float4*)&b[4] = *(const float4*)&Bs[kk][tx * 8 + 4];
#pragma unroll
      for (int i = 0; i < 8; ++i)
#pragma unroll
        for (int j = 0; j < 8; ++j) acc[i][j] = fmaf(a[i], b[j], acc[i][j]);
    }
    __syncthreads();
  }

#pragma unroll
  for (int i = 0; i < 8; ++i) {
    const int row = bm + ty * 8 + i;
#pragma unroll
    for (int j = 0; j < 8; j += 4) {
      const int col = bn + tx * 8 + j;
      if (col < N) {
        float4 r;
        float* rv = (float*)&r;
#pragma unroll
        for (int q = 0; q < 4; ++q) {
          float x = acc[i][j + q];
          if (ACT == 1) x = x / (1.f + expf(-x));
          rv[q] = x;
        }
        *(float4*)&C[(size_t)row * N + col] = r;
      }
    }
  }
}

// ---------------------------------------------------------------------------
// Phase P1: per-chunk partial sums of exp(k), per channel.  (bf16 k)
// ---------------------------------------------------------------------------
__global__ __launch_bounds__(256) void chunk_partial(
    const unsigned short* __restrict__ kb, float* __restrict__ partial) {
  const int blk = blockIdx.x;              // 0..511
  const int b = blk >> 8;
  const int rem = blk & 255;
  const int c = rem >> 2;
  const int seg = rem & 3;
  const int ch = seg * 256 + threadIdx.x;
  const unsigned short* base = kb + ((size_t)(b * NSEQ + c * CHUNK)) * DMODEL + ch;
  float acc = 0.f;
  for (int s = 0; s < CHUNK; ++s)
    acc += expf(bf2f(base[(size_t)s * DMODEL]));
  partial[((size_t)(b * NCH + c)) * DMODEL + ch] = acc;
}

// ---------------------------------------------------------------------------
// Phase P2: exclusive chunk prefix (+1 for zeros row).  Load-all then scan.
// ---------------------------------------------------------------------------
__global__ __launch_bounds__(256) void chunk_zoff(const float* __restrict__ partial,
                                                  float* __restrict__ zoff) {
  const int g = blockIdx.x * 256 + threadIdx.x;   // 0..2047
  const int b = g >> 10, dd = g & 1023;
  const size_t base = (size_t)b * NCH * DMODEL + dd;
  float vals[NCH];
#pragma unroll
  for (int c = 0; c < NCH; ++c)
    vals[c] = partial[base + (size_t)c * DMODEL];
  float run = 1.0f;
#pragma unroll
  for (int c = 0; c < NCH; ++c) {
    zoff[base + (size_t)c * DMODEL] = run;
    run += vals[c];
  }
}

// ---------------------------------------------------------------------------
// Main chunk kernel, MFMA version.  grid = 2048 blocks, 4 waves.
// G written TRANSPOSED (G^T[j][e], [64][128] per block) for the MFMA inter.
// ---------------------------------------------------------------------------
__global__ __launch_bounds__(256) void chunk_attn(
    const unsigned short* __restrict__ qb, const unsigned short* __restrict__ kb,
    const unsigned short* __restrict__ vb, const float* __restrict__ zoff,
    unsigned short* __restrict__ qp, unsigned short* __restrict__ G,
    unsigned short* __restrict__ ob) {
  const int bidx = blockIdx.x;
  const int bh = bidx / NCH, c = bidx % NCH;
  const int b = bh >> 4, h = bh & 15;
  const int c0 = h * HD;

  __shared__ float sk[CHUNK][64];                               // 8192 B
  __shared__ float ps[4][64];                                   // 1024 B
  __shared__ __align__(16) unsigned short qplds[CHUNK][136];    // 8704 B
  __shared__ __align__(16) unsigned short khlds[CHUNK][136];    // 8704 B
  __shared__ __align__(16) unsigned short kht[128][40];         // 10240 B
  __shared__ __align__(16) unsigned short vt[64][40];           // 5120 B
  __shared__ __align__(16) unsigned short slds[CHUNK][40];      // 2560 B

  const int tid = threadIdx.x;
  const int l = tid & 63;
  const int w = tid >> 6;

  // stage k (f32 for exp) and v -> VT (bf16 transposed)
  for (int idx = tid; idx < CHUNK * 64; idx += 256) {
    const int s = idx >> 6, dd2 = idx & 63;
    const size_t g = ((size_t)(b * NSEQ + c * CHUNK + s)) * DMODEL + c0 + dd2;
    sk[s][dd2] = bf2f(kb[g]);
    vt[dd2][s] = vb[g];
  }
  __syncthreads();

  // ---- phase A: Z cumsum + build QP/KH/KHT (thread = channel dd, 8 s) ----
  const int dd = l;
  const int wq_ = w;
  {
    float a = 0.f;
#pragma unroll
    for (int i = 0; i < CHUNK / 4; ++i) a += expf(sk[wq_ * (CHUNK / 4) + i][dd]);
    ps[wq_][dd] = a;
  }
  __syncthreads();
  {
    float z = zoff[((size_t)(b * NCH + c)) * DMODEL + c0 + dd];
    for (int q2 = 0; q2 < wq_; ++q2) z += ps[q2][dd];
    const float theta = expf(-2.0f * (float)(c0 + dd) * (1.0f / 1024.0f) * LN_BASE);
#pragma unroll 2
    for (int i = 0; i < CHUNK / 4; ++i) {
      const int s = wq_ * (CHUNK / 4) + i;
      const int t = c * CHUNK + s;
      const float ek = expf(sk[s][dd]);
      z += ek;
      float sn, cs_;
      fast_sincos((float)t * theta, &sn, &cs_);
      const float qv = bf2f(qb[((size_t)(b * NSEQ + t)) * DMODEL + c0 + dd]);
      const float inv = 1.0f / z;
      const unsigned short kcb = f2bf(ek * cs_);
      const unsigned short ksb = f2bf(ek * sn);
      const unsigned short qcb = f2bf(qv * cs_ * inv);
      const unsigned short qsb = f2bf(qv * sn * inv);
      khlds[s][dd] = kcb;
      khlds[s][64 + dd] = ksb;
      kht[dd][s] = kcb;
      kht[64 + dd][s] = ksb;
      qplds[s][dd] = qcb;
      qplds[s][64 + dd] = qsb;
      unsigned short* qpo = qp + ((size_t)bidx * CHUNK + s) * 128;
      qpo[dd] = qcb;
      qpo[64 + dd] = qsb;
    }
  }
  __syncthreads();

  // ---- score: S = QP(32x128) @ KH^T, causal-masked, -> slds bf16 ----
  {
    const int mw = w >> 1, nw = w & 1;
    f32x4 sd = (f32x4){0.f, 0.f, 0.f, 0.f};
#pragma unroll
    for (int ks = 0; ks < 4; ++ks) {
      bf16x8 aq = *(const bf16x8*)&qplds[mw * 16 + (l & 15)][(l >> 4) * 8 + ks * 32];
      bf16x8 bk = *(const bf16x8*)&khlds[nw * 16 + (l & 15)][(l >> 4) * 8 + ks * 32];
      sd = __builtin_amdgcn_mfma_f32_16x16x32_bf16(aq, bk, sd, 0, 0, 0);
    }
    const int trow = mw * 16 + (l >> 4) * 4;
    const int scol = nw * 16 + (l & 15);
#pragma unroll
    for (int r = 0; r < 4; ++r) {
      const float v = (scol <= trow + r) ? sd[r] : 0.f;
      slds[trow + r][scol] = f2bf(v);
    }
  }

  // ---- G^T = (KHT(128x32) @ V(32x64))^T -> global bf16 [64][128] ----
  {
    unsigned short* go = G + (size_t)bidx * 8192;
    const bf16x8 bv = *(const bf16x8*)&vt[w * 16 + (l & 15)][(l >> 4) * 8];
    const int jc = w * 16 + (l & 15);
#pragma unroll
    for (int et = 0; et < 8; ++et) {
      bf16x8 ak = *(const bf16x8*)&kht[et * 16 + (l & 15)][(l >> 4) * 8];
      f32x4 gd = (f32x4){0.f, 0.f, 0.f, 0.f};
      gd = __builtin_amdgcn_mfma_f32_16x16x32_bf16(ak, bv, gd, 0, 0, 0);
      const int e0r = et * 16 + (l >> 4) * 4;
      unsigned long long pk =
          (unsigned long long)f2bf(gd[0])
        | ((unsigned long long)f2bf(gd[1]) << 16)
        | ((unsigned long long)f2bf(gd[2]) << 32)
        | ((unsigned long long)f2bf(gd[3]) << 48);
      *(unsigned long long*)(go + (size_t)jc * 128 + e0r) = pk;
    }
  }
  __syncthreads();   // slds complete before O phase

  // ---- O_intra = S(32x32) @ V(32x64) -> ob bf16 ----
  {
    const bf16x8 bv = *(const bf16x8*)&vt[w * 16 + (l & 15)][(l >> 4) * 8];
    const int jc = w * 16 + (l & 15);
#pragma unroll
    for (int tt = 0; tt < 2; ++tt) {
      bf16x8 as = *(const bf16x8*)&slds[tt * 16 + (l & 15)][(l >> 4) * 8];
      f32x4 od = (f32x4){0.f, 0.f, 0.f, 0.f};
      od = __builtin_amdgcn_mfma_f32_16x16x32_bf16(as, bv, od, 0, 0, 0);
      const int trow = tt * 16 + (l >> 4) * 4;
#pragma unroll
      for (int r = 0; r < 4; ++r)
        ob[((size_t)(b * NSEQ + c * CHUNK + trow + r)) * DMODEL + c0 + jc] = f2bf(od[r]);
    }
  }
}

// ---------------------------------------------------------------------------
// Phase P3: exclusive prefix of G over chunks (in place; load-all then scan).
// ---------------------------------------------------------------------------
__global__ __launch_bounds__(256) void chunk_prefix(unsigned short* __restrict__ G) {
  const int g = blockIdx.x * 256 + threadIdx.x;   // 0 .. 32*4096-1
  const int bh = g >> 12;                          // 4096 pairs per bh
  const int e2 = (g & 4095) * 2;
  unsigned int* base = (unsigned int*)(G + (size_t)bh * NCH * 8192 + e2);
  unsigned int vals[NCH];
#pragma unroll
  for (int c = 0; c < NCH; ++c)
    vals[c] = base[(size_t)c * 4096];
  float run0 = 0.f, run1 = 0.f;
#pragma unroll
  for (int c = 0; c < NCH; ++c) {
    base[(size_t)c * 4096] =
        (unsigned int)f2bf(run0) | ((unsigned int)f2bf(run1) << 16);
    run0 += bf2f((unsigned short)(vals[c] & 0xFFFFu));
    run1 += bf2f((unsigned short)(vals[c] >> 16));
  }
}

// ---------------------------------------------------------------------------
// Inter-chunk + fused gated group-RMSNorm, MFMA version (round-27 verified).
// ---------------------------------------------------------------------------
__global__ __launch_bounds__(256) void chunk_inter_norm(
    const unsigned short* __restrict__ qp, const unsigned short* __restrict__ S0t,
    const unsigned short* __restrict__ ob, const unsigned short* __restrict__ gate,
    const float* __restrict__ norm_w, unsigned short* __restrict__ outb) {
  const int bidx = blockIdx.x;
  const int bh = bidx / NCH, c = bidx % NCH;
  const int b = bh >> 4, h = bh & 15;
  const int c0 = h * HD;

  const int tid = threadIdx.x;
  const int l = tid & 63;
  const int w = tid >> 6;
  const int mw = w >> 1;          // m-tile: rows mw*16..+16
  const int nw = w & 1;           // n-half: cols nw*32..+32 (n tiles 2nw,2nw+1)

  const unsigned short* qpb = qp + (size_t)bidx * CHUNK * 128;   // [32][128]
  const unsigned short* s0b = S0t + (size_t)bidx * 8192;         // [64][128]

  f32x4 acc[2];
  acc[0] = (f32x4){0.f, 0.f, 0.f, 0.f};
  acc[1] = (f32x4){0.f, 0.f, 0.f, 0.f};
#pragma unroll
  for (int ks = 0; ks < 4; ++ks) {
    const int ko = ks * 32 + (l >> 4) * 8;
    bf16x8 xa = *(const bf16x8*)(qpb + (size_t)(mw * 16 + (l & 15)) * 128 + ko);
#pragma unroll
    for (int n = 0; n < 2; ++n) {
      const int j = (nw * 2 + n) * 16 + (l & 15);
      bf16x8 yb = *(const bf16x8*)(s0b + (size_t)j * 128 + ko);
      acc[n] = __builtin_amdgcn_mfma_f32_16x16x32_bf16(xa, yb, acc[n], 0, 0, 0);
    }
  }

  // g = (O_inter + O_intra) * sigmoid(gate); per-row sum of squares.
  __shared__ float ssh[2][32];    // [n-half][row]
  float gval[2][4];
  float ssr[4];
#pragma unroll
  for (int r = 0; r < 4; ++r) {
    ssr[r] = 0.f;
    const int row = mw * 16 + (l >> 4) * 4 + r;
    const size_t rowg = ((size_t)(b * NSEQ + c * CHUNK + row)) * DMODEL + c0;
#pragma unroll
    for (int n = 0; n < 2; ++n) {
      const int col = (nw * 2 + n) * 16 + (l & 15);
      const float o = acc[n][r] + bf2f(ob[rowg + col]);
      const float gv = bf2f(gate[rowg + col]);
      const float g = o / (1.f + expf(-gv));
      gval[n][r] = g;
      ssr[r] = fmaf(g, g, ssr[r]);
    }
  }
#pragma unroll
  for (int r = 0; r < 4; ++r) {
    ssr[r] += __shfl_xor(ssr[r], 1);
    ssr[r] += __shfl_xor(ssr[r], 2);
    ssr[r] += __shfl_xor(ssr[r], 4);
    ssr[r] += __shfl_xor(ssr[r], 8);
  }
  if ((l & 15) == 0) {
#pragma unroll
    for (int r = 0; r < 4; ++r)
      ssh[nw][mw * 16 + (l >> 4) * 4 + r] = ssr[r];
  }
  __syncthreads();
#pragma unroll
  for (int r = 0; r < 4; ++r) {
    const int row = mw * 16 + (l >> 4) * 4 + r;
    const float ss = ssr[r] + ssh[nw ^ 1][row];
    const float inv = 1.0f / sqrtf(ss * (1.0f / 64.0f) + 1e-6f);
    const size_t rowg = ((size_t)(b * NSEQ + c * CHUNK + row)) * DMODEL + c0;
#pragma unroll
    for (int n = 0; n < 2; ++n) {
      const int col = (nw * 2 + n) * 16 + (l & 15);
      outb[rowg + col] = f2bf(gval[n][r] * inv * norm_w[c0 + col]);
    }
  }
}

// ---------------------------------------------------------------------------
// Fallback sequential scan (f32 path, used only if ws too small).
// ---------------------------------------------------------------------------
__global__ __launch_bounds__(256) void scan_kernel(const float* __restrict__ qb,
                                                   const float* __restrict__ kb,
                                                   const float* __restrict__ vb,
                                                   float* __restrict__ ob) {
  const int bh = blockIdx.x;
  const int b = bh >> 4;
  const int h = bh & 15;
  const int c0 = h * HD;

  __shared__ float sk[64][64];
  __shared__ float sq[64][64];
  __shared__ float sv[64][64];
  __shared__ float kh[128];
  __shared__ float qph[128];
  __shared__ float vsh[64];
  __shared__ float opart[4][64];

  const int tid = threadIdx.x;
  const int lane = tid & 63;
  const int w = tid >> 6;
  const int e0 = w * 32;

  float T[32];
#pragma unroll
  for (int i = 0; i < 32; ++i) T[i] = 0.f;

  float zrun = 1.0f;
  float theta_v = 0.f;
  if (tid < 64) theta_v = expf(-2.0f * (float)(c0 + tid) * (1.0f / 1024.0f) * LN_BASE);

  for (int t0 = 0; t0 < NSEQ; t0 += 64) {
    __syncthreads();
    for (int idx = tid; idx < 64 * 64; idx += 256) {
      const int tl = idx >> 6;
      const int dd = idx & 63;
      const size_t g = ((size_t)(b * NSEQ + t0 + tl)) * DMODEL + c0 + dd;
      sk[tl][dd] = kb[g];
      sq[tl][dd] = qb[g];
      sv[tl][dd] = vb[g];
    }
    __syncthreads();

    for (int tl = 0; tl < 64; ++tl) {
      const int t = t0 + tl;
      if (tid < 64) {
        const int dd = tid;
        const float kr = sk[tl][dd];
        const float ek = expf(kr);
        zrun += ek;
        const float inv = 1.0f / zrun;
        float cs_, sn;
        fast_sincos((float)t * theta_v, &sn, &cs_);
        const float qv = sq[tl][dd];
        kh[dd] = ek * cs_;
        kh[64 + dd] = ek * sn;
        qph[dd] = qv * cs_ * inv;
        qph[64 + dd] = qv * sn * inv;
        vsh[dd] = sv[tl][dd];
      }
      __syncthreads();

      const float vj = vsh[lane];
      float accj = 0.f;
#pragma unroll
      for (int i = 0; i < 32; ++i) {
        T[i] = fmaf(kh[e0 + i], vj, T[i]);
        accj = fmaf(qph[e0 + i], T[i], accj);
      }
      opart[w][lane] = accj;
      __syncthreads();

      if (tid < 64) {
        const float o = opart[0][tid] + opart[1][tid] + opart[2][tid] + opart[3][tid];
        ob[((size_t)(b * NSEQ + t)) * DMODEL + c0 + tid] = o;
      }
    }
  }
}

// ---------------------------------------------------------------------------
// Gated group-RMSNorm, f32 (fallback path only).
// ---------------------------------------------------------------------------
__global__ __launch_bounds__(256) void gated_rmsnorm_f32(
    const float* __restrict__ o, const float* __restrict__ gate,
    const float* __restrict__ norm_w, float* __restrict__ outf) {
  const int gidx = blockIdx.x * 4 + (threadIdx.x >> 6);
  const int lane = threadIdx.x & 63;
  const size_t base = (size_t)gidx * 64 + lane;
  const float ov = o[base];
  const float gv = gate[base];
  const float g = ov / (1.f + expf(-gv));
  float ss = g * g;
#pragma unroll
  for (int off = 32; off; off >>= 1) ss += __shfl_xor(ss, off);
  const float rms = sqrtf(ss * (1.0f / 64.0f) + 1e-6f);
  const int cch = (gidx & 15) * 64 + lane;
  outf[base] = g / rms * norm_w[cch];
}

// ---------------------------------------------------------------------------
extern "C" void kernel_launch(void* const* d_in, const int* in_sizes, int n_in,
                              void* d_out, int out_size, void* d_ws, size_t ws_size,
                              hipStream_t stream) {
  const float* x      = (const float*)d_in[0];
  const float* wq     = (const float*)d_in[1];
  const float* wk     = (const float*)d_in[2];
  const float* wv     = (const float*)d_in[3];
  const float* wo     = (const float*)d_in[4];
  const float* wg1    = (const float*)d_in[5];
  const float* wg2    = (const float*)d_in[6];
  const float* norm_w = (const float*)d_in[7];
  float* out = (float*)d_out;

  const int M = BATCH * NSEQ;            // 4096
  const size_t SZ = (size_t)M * DMODEL;  // 4,194,304 elements
  const size_t WSZ = (size_t)DMODEL * DMODEL;  // 1M

  // fp32 region (regions sized f32; bf16 views alias the same memory)
  float* qbuf = (float*)d_ws;
  float* kbuf = qbuf + SZ;
  float* vbuf = kbuf + SZ;
  float* obuf = vbuf + SZ;
  float* gbuf = obuf + SZ;
  float* g1   = gbuf + SZ;                                  // M*64
  float* part = g1 + (size_t)M * HD;                        // 2*64*1024
  float* zoff = part + (size_t)BATCH * NCH * DMODEL;
  float* qpb  = zoff + (size_t)BATCH * NCH * DMODEL;
  float* Gb   = qpb + (size_t)BATCH * NH * NCH * CHUNK * 128;
  float* f32_end = Gb + (size_t)BATCH * NH * NCH * 8192;

  // bf16 region (ushort)
  unsigned short* xbf   = (unsigned short*)f32_end;
  unsigned short* wAll  = xbf + SZ;          // [wqT|wkT|wvT] 3072x1024
  unsigned short* wqT   = wAll;
  unsigned short* wkT   = wAll + WSZ;
  unsigned short* wvT   = wAll + 2 * WSZ;
  unsigned short* wg1T  = wAll + 3 * WSZ;            // 64x1024
  unsigned short* wg2T  = wg1T + (size_t)64 * DMODEL; // 1024x64
  unsigned short* g1b   = wg2T + (size_t)64 * DMODEL; // 4096x64
  unsigned short* woT   = wAll + 4 * WSZ;
  unsigned short* nrmbf = woT + WSZ;
  unsigned short* u16_end = nrmbf + SZ;

  const size_t need_full = (size_t)((char*)u16_end - (char*)d_ws);

  // bf16 views (full path)
  unsigned short* qbuf16 = (unsigned short*)qbuf;
  unsigned short* kbuf16 = (unsigned short*)kbuf;
  unsigned short* vbuf16 = (unsigned short*)vbuf;
  unsigned short* obuf16 = (unsigned short*)obuf;
  unsigned short* gbuf16 = (unsigned short*)gbuf;
  unsigned short* qpb16  = (unsigned short*)qpb;
  unsigned short* Gb16   = (unsigned short*)Gb;

  dim3 blk(256);
  dim3 grid_d((DMODEL + 127) / 128, (M + 127) / 128);
  dim3 grid_g1(1, (M + 127) / 128);

  const bool full_ok = ws_size >= need_full;

  if (full_ok) {
    // ONE batched kernel: 4 weight transposes + x conversion + wg1T + wg2T.
    transpose_cvt7<<<dim3(32, 32, 7), blk, 0, stream>>>(
        wq, wk, wv, wo, x, wg1, wg2, wqT, wkT, wvT, woT, xbf, wg1T, wg2T);
    // Low-rank gate path: g1 = x @ wg1 (N=64), gate = g1 @ wg2 (K=64).
    gemm_bf16_g1<<<dim3(M / 16), blk, 0, stream>>>(xbf, wg1T, g1b);
    gemm_bf16_gate<<<dim3((M / 32) * (DMODEL / 128)), blk, 0, stream>>>(
        g1b, wg2T, gbuf16, M, DMODEL, 64);
    // Fused projections: 4096x3072x1024, bf16 outputs, BM=128 -> 768 blocks.
    gemm_bf16_fused<<<dim3((M / 128) * (3 * DMODEL / 128)), blk, 0, stream>>>(
        xbf, wAll, qbuf16, kbuf16, vbuf16, M, 3 * DMODEL, DMODEL);

    chunk_partial<<<dim3(BATCH * NCH * 4), blk, 0, stream>>>(kbuf16, part);
    chunk_zoff<<<dim3(8), blk, 0, stream>>>(part, zoff);
    chunk_attn<<<dim3(BATCH * NH * NCH), blk, 0, stream>>>(qbuf16, kbuf16, vbuf16,
                                                           zoff, qpb16, Gb16, obuf16);
    chunk_prefix<<<dim3(BATCH * NH * 8192 / 512), blk, 0, stream>>>(Gb16);
    chunk_inter_norm<<<dim3(BATCH * NH * NCH), blk, 0, stream>>>(
        qpb16, Gb16, obuf16, gbuf16, norm_w, nrmbf);

    // wo GEMM: BM=32 -> 1024 blocks (4/CU).
    gemm_bf16_wo<<<dim3((M / 32) * (DMODEL / 128)), blk, 0, stream>>>(
        nrmbf, woT, out, M, DMODEL, DMODEL);
  } else {
    // f32 fallback: separate buffers, sequential scan.
    gemm_f32<1><<<grid_d, blk, 0, stream>>>(x, wq, qbuf, M, DMODEL, DMODEL);
    gemm_f32<0><<<grid_d, blk, 0, stream>>>(x, wk, kbuf, M, DMODEL, DMODEL);
    gemm_f32<0><<<grid_d, blk, 0, stream>>>(x, wv, vbuf, M, DMODEL, DMODEL);
    gemm_f32<0><<<grid_g1, blk, 0, stream>>>(x, wg1, g1, M, HD, DMODEL);
    gemm_f32<0><<<grid_d, blk, 0, stream>>>(g1, wg2, gbuf, M, DMODEL, HD);
    scan_kernel<<<dim3(BATCH * NH), blk, 0, stream>>>(qbuf, kbuf, vbuf, obuf);
    float* nrm = kbuf;
    gated_rmsnorm_f32<<<dim3(M * NH / 4), blk, 0, stream>>>(obuf, gbuf, norm_w, nrm);
    gemm_f32<0><<<grid_d, blk, 0, stream>>>(nrm, wo, out, M, DMODEL, DMODEL);
  }
}

// Round 32
// 133.107 us; speedup vs baseline: 1.0200x; 1.0200x over previous
//
#include <hip/hip_runtime.h>
#include <math.h>

#define NH 16
#define HD 64
#define DMODEL 1024
#define NSEQ 2048
#define BATCH 2
#define CHUNK 32
#define NCH (NSEQ / CHUNK)            // 64 chunks
#define LN_BASE 9.210340371976184f    // ln(10000)

typedef __attribute__((ext_vector_type(8))) short bf16x8;
typedef __attribute__((ext_vector_type(8))) unsigned short u16x8;
typedef __attribute__((ext_vector_type(4))) float f32x4;

__device__ __forceinline__ unsigned short f2bf(float f) {
  union { float f; unsigned int u; } v; v.f = f;
  unsigned int u = v.u;
  unsigned int r = u + 0x7FFFu + ((u >> 16) & 1u);   // RNE
  return (unsigned short)(r >> 16);
}
__device__ __forceinline__ float bf2f(unsigned short u) {
  union { unsigned int u; float f; } v; v.u = ((unsigned int)u) << 16;
  return v.f;
}

// Fast range-reduced sincos (HW v_sin/v_cos after reduction to one revolution).
__device__ __forceinline__ void fast_sincos(float ang, float* s, float* c) {
  const float INV2PI = 0.15915494309189535f;
  const float TWOPI  = 6.283185307179586f;
  float rev = ang * INV2PI;
  rev = rev - floorf(rev);          // [0,1)
  float ar = rev * TWOPI;
  *s = __sinf(ar);
  *c = __cosf(ar);
}

// Async global->LDS, 16B per lane (dest = wave-uniform base + lane*16).
__device__ __forceinline__ void gload_lds16(const unsigned short* g,
                                            unsigned short* l) {
  __builtin_amdgcn_global_load_lds(
      (const __attribute__((address_space(1))) void*)g,
      (__attribute__((address_space(3))) void*)l, 16, 0, 0);
}

// ---------------------------------------------------------------------------
// Batched transposes + x conversion:
//   z=0..3 : [1024][1024] f32 -> bf16^T   (wq wk wv wo)
//   z=4    : x f32 -> bf16 linear
//   z=5    : wg1 [1024][64]  -> wg1T [64][1024]  (only blockIdx.x<2 active)
//   z=6    : wg2 [64][1024]  -> wg2T [1024][64]  (only blockIdx.y<2 active)
// ---------------------------------------------------------------------------
__global__ __launch_bounds__(256) void transpose_cvt7(
    const float* __restrict__ s0, const float* __restrict__ s1,
    const float* __restrict__ s2, const float* __restrict__ s3,
    const float* __restrict__ xs, const float* __restrict__ wg1,
    const float* __restrict__ wg2,
    unsigned short* __restrict__ d0, unsigned short* __restrict__ d1,
    unsigned short* __restrict__ d2, unsigned short* __restrict__ d3,
    unsigned short* __restrict__ xd, unsigned short* __restrict__ wg1T,
    unsigned short* __restrict__ wg2T) {
  const int z = blockIdx.z;
  if (z == 4) {
    const int lin = blockIdx.y * 32 + blockIdx.x;   // 0..1023
    const size_t base = (size_t)lin * 4096 + threadIdx.x * 4;
#pragma unroll
    for (int r = 0; r < 4; ++r) {
      float4 v = *(const float4*)(xs + base + r * 1024);
      unsigned short* o = xd + base + r * 1024;
      o[0] = f2bf(v.x); o[1] = f2bf(v.y); o[2] = f2bf(v.z); o[3] = f2bf(v.w);
    }
    return;
  }
  const float* in;
  unsigned short* out;
  int R, Cn;
  if (z < 4) {
    in = (z == 0) ? s0 : (z == 1) ? s1 : (z == 2) ? s2 : s3;
    out = (z == 0) ? d0 : (z == 1) ? d1 : (z == 2) ? d2 : d3;
    R = DMODEL; Cn = DMODEL;
  } else if (z == 5) {
    if (blockIdx.x >= 2) return;     // Cn=64 -> 2 col-tiles
    in = wg1; out = wg1T; R = DMODEL; Cn = 64;
  } else {
    if (blockIdx.y >= 2) return;     // R=64 -> 2 row-tiles
    in = wg2; out = wg2T; R = 64; Cn = DMODEL;
  }
  __shared__ float tl[32][33];
  const int t = threadIdx.x;
  const int ci = t & 31, ri = t >> 5;   // ri in 0..7
  const int br = blockIdx.y * 32, bc = blockIdx.x * 32;
#pragma unroll
  for (int rr = 0; rr < 4; ++rr)
    tl[ri + rr * 8][ci] = in[(size_t)(br + ri + rr * 8) * Cn + bc + ci];
  __syncthreads();
#pragma unroll
  for (int rr = 0; rr < 4; ++rr) {
    const int orow = bc + ri + rr * 8;   // output row = input col
    const int ocol = br + ci;            // output col = input row
    out[(size_t)orow * R + ocol] = f2bf(tl[ci][ri + rr * 8]);
  }
}

// ---------------------------------------------------------------------------
// g1 = x[4096][1024] @ wg1T[64][1024]^T -> bf16 [4096][64]  (low-rank gate
// step 1).  BM=16, N=64, BK=64 -> 256 blocks (1/CU).
// ---------------------------------------------------------------------------
__global__ __launch_bounds__(256) void gemm_bf16_g1(
    const unsigned short* __restrict__ A, const unsigned short* __restrict__ Bt,
    unsigned short* __restrict__ C) {
  __shared__ unsigned short As[16][64];    // 2 KB
  __shared__ unsigned short Bs[64][64];    // 8 KB
  const int tid = threadIdx.x;
  const int l = tid & 63;
  const int w = tid >> 6;
  const int bm = blockIdx.x * 16;
  const int K = DMODEL;

  const int lrow = l >> 3;
  const int cd = l & 7;
  const int cl = cd ^ lrow;

  f32x4 acc = (f32x4){0.f, 0.f, 0.f, 0.f};

  for (int k0 = 0; k0 < K; k0 += 64) {
    __syncthreads();
    if (w < 2) {                        // A: wave w stages rows [w*8, w*8+8)
      const int row = w * 8 + lrow;
      unsigned short* la = (unsigned short*)As + (w * 8) * 64 + l * 8;
      gload_lds16(A + (size_t)(bm + row) * K + k0 + cl * 8, la);
    }
    {                                   // B: wave w stages rows [w*16, w*16+16)
#pragma unroll
      for (int c = 0; c < 2; ++c) {
        const int row = w * 16 + c * 8 + lrow;
        unsigned short* lb = (unsigned short*)Bs + (w * 16 + c * 8) * 64 + l * 8;
        gload_lds16(Bt + (size_t)row * K + k0 + cl * 8, lb);
      }
    }
    __syncthreads();

#pragma unroll
    for (int ks = 0; ks < 2; ++ks) {
      bf16x8 af, bfr;
      {
        const int r = l & 15;
        const int phys = (ks * 4 + (l >> 4)) ^ (r & 7);
        af = *(const bf16x8*)&As[r][phys * 8];
      }
      {
        const int r = w * 16 + (l & 15);
        const int phys = (ks * 4 + (l >> 4)) ^ (r & 7);
        bfr = *(const bf16x8*)&Bs[r][phys * 8];
      }
      acc = __builtin_amdgcn_mfma_f32_16x16x32_bf16(af, bfr, acc, 0, 0, 0);
    }
  }

  {
    const int row0 = bm + (l >> 4) * 4;
    const int col = w * 16 + (l & 15);
#pragma unroll
    for (int r = 0; r < 4; ++r)
      C[(size_t)(row0 + r) * 64 + col] = f2bf(acc[r]);
  }
}

// ---------------------------------------------------------------------------
// gate = g1[4096][64] @ wg2T[1024][64]^T -> bf16 (low-rank gate step 2).
// BM=32, BN=128 -> 1024 blocks (4/CU).
// ---------------------------------------------------------------------------
__global__ __launch_bounds__(256, 6) void gemm_bf16_gate(
    const unsigned short* __restrict__ A, const unsigned short* __restrict__ Bt,
    unsigned short* __restrict__ C, int M, int N, int K) {
  __shared__ unsigned short As[32][64];    // 4 KB
  __shared__ unsigned short Bs[128][64];   // 16 KB
  const int tid = threadIdx.x;
  const int l = tid & 63;
  const int w = tid >> 6;
  const int wr = (w >> 1) * 16;            // 0/16
  const int wc = (w & 1) * 64;

  const int nwg = gridDim.x;               // 1024
  const int orig = blockIdx.x;
  const int swz = (orig & 7) * (nwg >> 3) + (orig >> 3);
  const int ntn = N >> 7;                  // 8
  const int bm = (swz / ntn) * 32;
  const int bn = (swz % ntn) * 128;

  const int lrow = l >> 3;
  const int cd = l & 7;
  const int cl = cd ^ lrow;

  f32x4 acc[4];
#pragma unroll
  for (int n = 0; n < 4; ++n) acc[n] = (f32x4){0.f, 0.f, 0.f, 0.f};

  for (int k0 = 0; k0 < K; k0 += 64) {
    __syncthreads();
    {                                   // A: wave stages rows [w*8, w*8+8)
      const int row = w * 8 + lrow;
      unsigned short* la = (unsigned short*)As + (w * 8) * 64 + l * 8;
      gload_lds16(A + (size_t)(bm + row) * K + k0 + cl * 8, la);
    }
#pragma unroll
    for (int c = 0; c < 4; ++c) {       // B: wave stages rows [w*32, w*32+32)
      const int row = w * 32 + c * 8 + lrow;
      unsigned short* lb = (unsigned short*)Bs + (w * 32 + c * 8) * 64 + l * 8;
      gload_lds16(Bt + (size_t)(bn + row) * K + k0 + cl * 8, lb);
    }
    __syncthreads();

#pragma unroll
    for (int ks = 0; ks < 2; ++ks) {
      bf16x8 af, bfr[4];
      {
        const int r = wr + (l & 15);
        const int phys = (ks * 4 + (l >> 4)) ^ (r & 7);
        af = *(const bf16x8*)&As[r][phys * 8];
      }
#pragma unroll
      for (int n = 0; n < 4; ++n) {
        const int r = wc + n * 16 + (l & 15);
        const int phys = (ks * 4 + (l >> 4)) ^ (r & 7);
        bfr[n] = *(const bf16x8*)&Bs[r][phys * 8];
      }
#pragma unroll
      for (int n = 0; n < 4; ++n)
        acc[n] = __builtin_amdgcn_mfma_f32_16x16x32_bf16(af, bfr[n], acc[n], 0, 0, 0);
    }
  }

  {
    const int row0 = bm + wr + (l >> 4) * 4;
#pragma unroll
    for (int n = 0; n < 4; ++n) {
      const int col = bn + wc + n * 16 + (l & 15);
#pragma unroll
      for (int r = 0; r < 4; ++r)
        C[(size_t)(row0 + r) * N + col] = f2bf(acc[n][r]);
    }
  }
}

// ---------------------------------------------------------------------------
// bf16 MFMA GEMM, fused 3-output (round-31: Ntot=3072 -> 768 blocks).
// BM=128 single buffer (round-28/30 verified optimum).  2D XCD regions:
// 768 = 8 XCD x 96; region = 8 bm x 12 bn.  Bands -> B0..B2, silu on B0.
// ---------------------------------------------------------------------------
__global__ __launch_bounds__(256, 4) void gemm_bf16_fused(
    const unsigned short* __restrict__ A, const unsigned short* __restrict__ Bt,
    unsigned short* __restrict__ B0, unsigned short* __restrict__ B1,
    unsigned short* __restrict__ B2,
    int M, int Ntot, int K) {
  __shared__ unsigned short As[128][64];   // 16 KB
  __shared__ unsigned short Bs[128][64];   // 16 KB
  const int tid = threadIdx.x;
  const int l = tid & 63;
  const int w = tid >> 6;
  const int wr = (w >> 1) * 64;
  const int wc = (w & 1) * 64;

  const int orig = blockIdx.x;
  const int xcd = orig & 7;
  const int idx = orig >> 3;               // 0..95
  const int bm = ((xcd >> 1) * 8 + (idx & 7)) * 128;
  const int bn = ((xcd & 1) * 12 + (idx >> 3)) * 128;

  const int lrow = l >> 3;                 // 0..7 row within call
  const int cd = l & 7;                    // dest 16B chunk
  const int cl = cd ^ lrow;                // logical chunk fetched (row&7==lrow)

  f32x4 acc[4][4];
#pragma unroll
  for (int m = 0; m < 4; ++m)
#pragma unroll
    for (int n = 0; n < 4; ++n) acc[m][n] = (f32x4){0.f, 0.f, 0.f, 0.f};

  for (int k0 = 0; k0 < K; k0 += 64) {
    __syncthreads();   // previous iteration's ds_reads complete
#pragma unroll
    for (int c = 0; c < 4; ++c) {       // A: wave stages rows [w*32, w*32+32)
      const int row = w * 32 + c * 8 + lrow;
      unsigned short* la = (unsigned short*)As + (w * 32 + c * 8) * 64 + l * 8;
      gload_lds16(A + (size_t)(bm + row) * K + k0 + cl * 8, la);
    }
#pragma unroll
    for (int c = 0; c < 4; ++c) {       // B: wave stages rows [w*32, w*32+32)
      const int row = w * 32 + c * 8 + lrow;
      unsigned short* lb = (unsigned short*)Bs + (w * 32 + c * 8) * 64 + l * 8;
      gload_lds16(Bt + (size_t)(bn + row) * K + k0 + cl * 8, lb);
    }
    __syncthreads();   // vmcnt(0) drained before barrier -> tiles ready

#pragma unroll
    for (int ks = 0; ks < 2; ++ks) {
      bf16x8 af[4], bfr[4];
#pragma unroll
      for (int m = 0; m < 4; ++m) {
        const int r = wr + m * 16 + (l & 15);
        const int phys = (ks * 4 + (l >> 4)) ^ (r & 7);
        af[m] = *(const bf16x8*)&As[r][phys * 8];
      }
#pragma unroll
      for (int n = 0; n < 4; ++n) {
        const int r = wc + n * 16 + (l & 15);
        const int phys = (ks * 4 + (l >> 4)) ^ (r & 7);
        bfr[n] = *(const bf16x8*)&Bs[r][phys * 8];
      }
#pragma unroll
      for (int m = 0; m < 4; ++m)
#pragma unroll
        for (int n = 0; n < 4; ++n)
          acc[m][n] = __builtin_amdgcn_mfma_f32_16x16x32_bf16(af[m], bfr[n], acc[m][n], 0, 0, 0);
    }
  }

#pragma unroll
  for (int m = 0; m < 4; ++m) {
    const int row0 = bm + wr + m * 16 + (l >> 4) * 4;
#pragma unroll
    for (int n = 0; n < 4; ++n) {
      const int colw = wc + n * 16 + (l & 15);
#pragma unroll
      for (int r = 0; r < 4; ++r) {
        float x = acc[m][n][r];
        const int nb = bn >> 10;
        unsigned short* Bb = (nb == 0) ? B0 : (nb == 1) ? B1 : B2;
        const int col = (bn & 1023) + colw;
        if (nb == 0) x = x / (1.f + expf(-x));
        Bb[(size_t)(row0 + r) * DMODEL + col] = f2bf(x);
      }
    }
  }
}

// ---------------------------------------------------------------------------
// wo GEMM (round-26 verified: BM=32 -> 1024 blocks = 4/CU).  f32 output.
// ---------------------------------------------------------------------------
__global__ __launch_bounds__(256, 6) void gemm_bf16_wo(
    const unsigned short* __restrict__ A, const unsigned short* __restrict__ Bt,
    float* __restrict__ C, int M, int N, int K) {
  __shared__ unsigned short As[32][64];    // 4 KB
  __shared__ unsigned short Bs[128][64];   // 16 KB
  const int tid = threadIdx.x;
  const int l = tid & 63;
  const int w = tid >> 6;
  const int wr = (w >> 1) * 16;            // 0/16
  const int wc = (w & 1) * 64;

  const int nwg = gridDim.x;               // 1024
  const int orig = blockIdx.x;
  const int swz = (orig & 7) * (nwg >> 3) + (orig >> 3);
  const int ntn = N >> 7;                  // 8
  const int bm = (swz / ntn) * 32;
  const int bn = (swz % ntn) * 128;

  const int lrow = l >> 3;
  const int cd = l & 7;
  const int cl = cd ^ lrow;

  f32x4 acc[4];
#pragma unroll
  for (int n = 0; n < 4; ++n) acc[n] = (f32x4){0.f, 0.f, 0.f, 0.f};

  for (int k0 = 0; k0 < K; k0 += 64) {
    __syncthreads();
    {                                   // A: wave stages rows [w*8, w*8+8)
      const int row = w * 8 + lrow;
      unsigned short* la = (unsigned short*)As + (w * 8) * 64 + l * 8;
      gload_lds16(A + (size_t)(bm + row) * K + k0 + cl * 8, la);
    }
#pragma unroll
    for (int c = 0; c < 4; ++c) {       // B: wave stages rows [w*32, w*32+32)
      const int row = w * 32 + c * 8 + lrow;
      unsigned short* lb = (unsigned short*)Bs + (w * 32 + c * 8) * 64 + l * 8;
      gload_lds16(Bt + (size_t)(bn + row) * K + k0 + cl * 8, lb);
    }
    __syncthreads();

#pragma unroll
    for (int ks = 0; ks < 2; ++ks) {
      bf16x8 af, bfr[4];
      {
        const int r = wr + (l & 15);
        const int phys = (ks * 4 + (l >> 4)) ^ (r & 7);
        af = *(const bf16x8*)&As[r][phys * 8];
      }
#pragma unroll
      for (int n = 0; n < 4; ++n) {
        const int r = wc + n * 16 + (l & 15);
        const int phys = (ks * 4 + (l >> 4)) ^ (r & 7);
        bfr[n] = *(const bf16x8*)&Bs[r][phys * 8];
      }
#pragma unroll
      for (int n = 0; n < 4; ++n)
        acc[n] = __builtin_amdgcn_mfma_f32_16x16x32_bf16(af, bfr[n], acc[n], 0, 0, 0);
    }
  }

  {
    const int row0 = bm + wr + (l >> 4) * 4;
#pragma unroll
    for (int n = 0; n < 4; ++n) {
      const int col = bn + wc + n * 16 + (l & 15);
#pragma unroll
      for (int r = 0; r < 4; ++r)
        C[(size_t)(row0 + r) * N + col] = acc[n][r];
    }
  }
}

// ---------------------------------------------------------------------------
// Tiled fp32 GEMM (fallback path only).
// ---------------------------------------------------------------------------
template <int ACT>
__global__ __launch_bounds__(256) void gemm_f32(const float* __restrict__ A,
                                                const float* __restrict__ B,
                                                float* __restrict__ C,
                                                int M, int N, int K) {
  __shared__ __align__(16) float As[16][128];
  __shared__ __align__(16) float Bs[16][128];
  const int tid = threadIdx.x;
  const int tx = tid & 15;
  const int ty = tid >> 4;
  const int bm = blockIdx.y * 128;
  const int bn = blockIdx.x * 128;

  float acc[8][8];
#pragma unroll
  for (int i = 0; i < 8; ++i)
#pragma unroll
    for (int j = 0; j < 8; ++j) acc[i][j] = 0.f;

  for (int k0 = 0; k0 < K; k0 += 16) {
    {
      const int row = tid >> 1;
      const int ko = (tid & 1) * 8;
      const float* src = A + (size_t)(bm + row) * K + k0 + ko;
      float4 a0 = *(const float4*)src;
      float4 a1 = *(const float4*)(src + 4);
      As[ko + 0][row] = a0.x; As[ko + 1][row] = a0.y;
      As[ko + 2][row] = a0.z; As[ko + 3][row] = a0.w;
      As[ko + 4][row] = a1.x; As[ko + 5][row] = a1.y;
      As[ko + 6][row] = a1.z; As[ko + 7][row] = a1.w;
    }
    {
      const int kr = tid >> 4;
      const int no = (tid & 15) * 8;
      float4 b0 = make_float4(0.f, 0.f, 0.f, 0.f);
      float4 b1 = b0;
      if (no < N) {
        const float* src = B + (size_t)(k0 + kr) * N + bn + no;
        b0 = *(const float4*)src;
        b1 = *(const float4*)(src + 4);
      }
      *(float4*)&Bs[kr][no] = b0;
      *(float4*)&Bs[kr][no + 4] = b1;
    }
    __syncthreads();
#pragma unroll
    for (int kk = 0; kk < 16; ++kk) {
      float a[8], b[8];
      *(float4*)&a[0] = *(const float4*)&As[kk][ty * 8];
      *(float4*)&a[4] = *(const float4*)&As[kk][ty * 8 + 4];
      *(float4*)&b[0] = *(const float4*)&Bs[kk][tx * 8];
      *(float4*)&b[4] = *(const float4*)&Bs[kk][tx * 8 + 4];
#pragma unroll
      for (int i = 0; i < 8; ++i)
#pragma unroll
        for (int j = 0; j < 8; ++j) acc[i][j] = fmaf(a[i], b[j], acc[i][j]);
    }
    __syncthreads();
  }

#pragma unroll
  for (int i = 0; i < 8; ++i) {
    const int row = bm + ty * 8 + i;
#pragma unroll
    for (int j = 0; j < 8; j += 4) {
      const int col = bn + tx * 8 + j;
      if (col < N) {
        float4 r;
        float* rv = (float*)&r;
#pragma unroll
        for (int q = 0; q < 4; ++q) {
          float x = acc[i][j + q];
          if (ACT == 1) x = x / (1.f + expf(-x));
          rv[q] = x;
        }
        *(float4*)&C[(size_t)row * N + col] = r;
      }
    }
  }
}

// ---------------------------------------------------------------------------
// Phase P1: per-chunk partial sums of exp(k), per channel.  (bf16 k)
// ---------------------------------------------------------------------------
__global__ __launch_bounds__(256) void chunk_partial(
    const unsigned short* __restrict__ kb, float* __restrict__ partial) {
  const int blk = blockIdx.x;              // 0..511
  const int b = blk >> 8;
  const int rem = blk & 255;
  const int c = rem >> 2;
  const int seg = rem & 3;
  const int ch = seg * 256 + threadIdx.x;
  const unsigned short* base = kb + ((size_t)(b * NSEQ + c * CHUNK)) * DMODEL + ch;
  float acc = 0.f;
  for (int s = 0; s < CHUNK; ++s)
    acc += expf(bf2f(base[(size_t)s * DMODEL]));
  partial[((size_t)(b * NCH + c)) * DMODEL + ch] = acc;
}

// ---------------------------------------------------------------------------
// Phase P2: exclusive chunk prefix (+1 for zeros row).  Load-all then scan.
// ---------------------------------------------------------------------------
__global__ __launch_bounds__(256) void chunk_zoff(const float* __restrict__ partial,
                                                  float* __restrict__ zoff) {
  const int g = blockIdx.x * 256 + threadIdx.x;   // 0..2047
  const int b = g >> 10, dd = g & 1023;
  const size_t base = (size_t)b * NCH * DMODEL + dd;
  float vals[NCH];
#pragma unroll
  for (int c = 0; c < NCH; ++c)
    vals[c] = partial[base + (size_t)c * DMODEL];
  float run = 1.0f;
#pragma unroll
  for (int c = 0; c < NCH; ++c) {
    zoff[base + (size_t)c * DMODEL] = run;
    run += vals[c];
  }
}

// ---------------------------------------------------------------------------
// Main chunk kernel, MFMA version.  grid = 2048 blocks, 4 waves.
// Round-32: k/v staging vectorized u16x8 (was scalar 2B loads — G13).
// G written TRANSPOSED (G^T[j][e], [64][128] per block) for the MFMA inter.
// ---------------------------------------------------------------------------
__global__ __launch_bounds__(256) void chunk_attn(
    const unsigned short* __restrict__ qb, const unsigned short* __restrict__ kb,
    const unsigned short* __restrict__ vb, const float* __restrict__ zoff,
    unsigned short* __restrict__ qp, unsigned short* __restrict__ G,
    unsigned short* __restrict__ ob) {
  const int bidx = blockIdx.x;
  const int bh = bidx / NCH, c = bidx % NCH;
  const int b = bh >> 4, h = bh & 15;
  const int c0 = h * HD;

  __shared__ float sk[CHUNK][64];                               // 8192 B
  __shared__ float ps[4][64];                                   // 1024 B
  __shared__ __align__(16) unsigned short qplds[CHUNK][136];    // 8704 B
  __shared__ __align__(16) unsigned short khlds[CHUNK][136];    // 8704 B
  __shared__ __align__(16) unsigned short kht[128][40];         // 10240 B
  __shared__ __align__(16) unsigned short vt[64][40];           // 5120 B
  __shared__ __align__(16) unsigned short slds[CHUNK][40];      // 2560 B

  const int tid = threadIdx.x;
  const int l = tid & 63;
  const int w = tid >> 6;

  // stage k (f32 for exp) and v -> VT (bf16 transposed), 16B vector loads:
  // thread tid covers s = tid>>3, channels (tid&7)*8 .. +8.
  {
    const int s = tid >> 3, d0 = (tid & 7) * 8;
    const size_t g = ((size_t)(b * NSEQ + c * CHUNK + s)) * DMODEL + c0 + d0;
    u16x8 kv8 = *(const u16x8*)(kb + g);
    u16x8 vv8 = *(const u16x8*)(vb + g);
#pragma unroll
    for (int q = 0; q < 8; ++q) {
      sk[s][d0 + q] = bf2f(kv8[q]);
      vt[d0 + q][s] = vv8[q];
    }
  }
  __syncthreads();

  // ---- phase A: Z cumsum + build QP/KH/KHT (thread = channel dd, 8 s) ----
  const int dd = l;
  const int wq_ = w;
  {
    float a = 0.f;
#pragma unroll
    for (int i = 0; i < CHUNK / 4; ++i) a += expf(sk[wq_ * (CHUNK / 4) + i][dd]);
    ps[wq_][dd] = a;
  }
  __syncthreads();
  {
    float z = zoff[((size_t)(b * NCH + c)) * DMODEL + c0 + dd];
    for (int q2 = 0; q2 < wq_; ++q2) z += ps[q2][dd];
    const float theta = expf(-2.0f * (float)(c0 + dd) * (1.0f / 1024.0f) * LN_BASE);
#pragma unroll 2
    for (int i = 0; i < CHUNK / 4; ++i) {
      const int s = wq_ * (CHUNK / 4) + i;
      const int t = c * CHUNK + s;
      const float ek = expf(sk[s][dd]);
      z += ek;
      float sn, cs_;
      fast_sincos((float)t * theta, &sn, &cs_);
      const float qv = bf2f(qb[((size_t)(b * NSEQ + t)) * DMODEL + c0 + dd]);
      const float inv = 1.0f / z;
      const unsigned short kcb = f2bf(ek * cs_);
      const unsigned short ksb = f2bf(ek * sn);
      const unsigned short qcb = f2bf(qv * cs_ * inv);
      const unsigned short qsb = f2bf(qv * sn * inv);
      khlds[s][dd] = kcb;
      khlds[s][64 + dd] = ksb;
      kht[dd][s] = kcb;
      kht[64 + dd][s] = ksb;
      qplds[s][dd] = qcb;
      qplds[s][64 + dd] = qsb;
      unsigned short* qpo = qp + ((size_t)bidx * CHUNK + s) * 128;
      qpo[dd] = qcb;
      qpo[64 + dd] = qsb;
    }
  }
  __syncthreads();

  // ---- score: S = QP(32x128) @ KH^T, causal-masked, -> slds bf16 ----
  {
    const int mw = w >> 1, nw = w & 1;
    f32x4 sd = (f32x4){0.f, 0.f, 0.f, 0.f};
#pragma unroll
    for (int ks = 0; ks < 4; ++ks) {
      bf16x8 aq = *(const bf16x8*)&qplds[mw * 16 + (l & 15)][(l >> 4) * 8 + ks * 32];
      bf16x8 bk = *(const bf16x8*)&khlds[nw * 16 + (l & 15)][(l >> 4) * 8 + ks * 32];
      sd = __builtin_amdgcn_mfma_f32_16x16x32_bf16(aq, bk, sd, 0, 0, 0);
    }
    const int trow = mw * 16 + (l >> 4) * 4;
    const int scol = nw * 16 + (l & 15);
#pragma unroll
    for (int r = 0; r < 4; ++r) {
      const float v = (scol <= trow + r) ? sd[r] : 0.f;
      slds[trow + r][scol] = f2bf(v);
    }
  }

  // ---- G^T = (KHT(128x32) @ V(32x64))^T -> global bf16 [64][128] ----
  {
    unsigned short* go = G + (size_t)bidx * 8192;
    const bf16x8 bv = *(const bf16x8*)&vt[w * 16 + (l & 15)][(l >> 4) * 8];
    const int jc = w * 16 + (l & 15);
#pragma unroll
    for (int et = 0; et < 8; ++et) {
      bf16x8 ak = *(const bf16x8*)&kht[et * 16 + (l & 15)][(l >> 4) * 8];
      f32x4 gd = (f32x4){0.f, 0.f, 0.f, 0.f};
      gd = __builtin_amdgcn_mfma_f32_16x16x32_bf16(ak, bv, gd, 0, 0, 0);
      const int e0r = et * 16 + (l >> 4) * 4;
      unsigned long long pk =
          (unsigned long long)f2bf(gd[0])
        | ((unsigned long long)f2bf(gd[1]) << 16)
        | ((unsigned long long)f2bf(gd[2]) << 32)
        | ((unsigned long long)f2bf(gd[3]) << 48);
      *(unsigned long long*)(go + (size_t)jc * 128 + e0r) = pk;
    }
  }
  __syncthreads();   // slds complete before O phase

  // ---- O_intra = S(32x32) @ V(32x64) -> ob bf16 ----
  {
    const bf16x8 bv = *(const bf16x8*)&vt[w * 16 + (l & 15)][(l >> 4) * 8];
    const int jc = w * 16 + (l & 15);
#pragma unroll
    for (int tt = 0; tt < 2; ++tt) {
      bf16x8 as = *(const bf16x8*)&slds[tt * 16 + (l & 15)][(l >> 4) * 8];
      f32x4 od = (f32x4){0.f, 0.f, 0.f, 0.f};
      od = __builtin_amdgcn_mfma_f32_16x16x32_bf16(as, bv, od, 0, 0, 0);
      const int trow = tt * 16 + (l >> 4) * 4;
#pragma unroll
      for (int r = 0; r < 4; ++r)
        ob[((size_t)(b * NSEQ + c * CHUNK + trow + r)) * DMODEL + c0 + jc] = f2bf(od[r]);
    }
  }
}

// ---------------------------------------------------------------------------
// Phase P3: exclusive prefix of G over chunks (in place; load-all then scan).
// ---------------------------------------------------------------------------
__global__ __launch_bounds__(256) void chunk_prefix(unsigned short* __restrict__ G) {
  const int g = blockIdx.x * 256 + threadIdx.x;   // 0 .. 32*4096-1
  const int bh = g >> 12;                          // 4096 pairs per bh
  const int e2 = (g & 4095) * 2;
  unsigned int* base = (unsigned int*)(G + (size_t)bh * NCH * 8192 + e2);
  unsigned int vals[NCH];
#pragma unroll
  for (int c = 0; c < NCH; ++c)
    vals[c] = base[(size_t)c * 4096];
  float run0 = 0.f, run1 = 0.f;
#pragma unroll
  for (int c = 0; c < NCH; ++c) {
    base[(size_t)c * 4096] =
        (unsigned int)f2bf(run0) | ((unsigned int)f2bf(run1) << 16);
    run0 += bf2f((unsigned short)(vals[c] & 0xFFFFu));
    run1 += bf2f((unsigned short)(vals[c] >> 16));
  }
}

// ---------------------------------------------------------------------------
// Inter-chunk + fused gated group-RMSNorm, MFMA version (round-27 verified).
// ---------------------------------------------------------------------------
__global__ __launch_bounds__(256) void chunk_inter_norm(
    const unsigned short* __restrict__ qp, const unsigned short* __restrict__ S0t,
    const unsigned short* __restrict__ ob, const unsigned short* __restrict__ gate,
    const float* __restrict__ norm_w, unsigned short* __restrict__ outb) {
  const int bidx = blockIdx.x;
  const int bh = bidx / NCH, c = bidx % NCH;
  const int b = bh >> 4, h = bh & 15;
  const int c0 = h * HD;

  const int tid = threadIdx.x;
  const int l = tid & 63;
  const int w = tid >> 6;
  const int mw = w >> 1;          // m-tile: rows mw*16..+16
  const int nw = w & 1;           // n-half: cols nw*32..+32 (n tiles 2nw,2nw+1)

  const unsigned short* qpb = qp + (size_t)bidx * CHUNK * 128;   // [32][128]
  const unsigned short* s0b = S0t + (size_t)bidx * 8192;         // [64][128]

  f32x4 acc[2];
  acc[0] = (f32x4){0.f, 0.f, 0.f, 0.f};
  acc[1] = (f32x4){0.f, 0.f, 0.f, 0.f};
#pragma unroll
  for (int ks = 0; ks < 4; ++ks) {
    const int ko = ks * 32 + (l >> 4) * 8;
    bf16x8 xa = *(const bf16x8*)(qpb + (size_t)(mw * 16 + (l & 15)) * 128 + ko);
#pragma unroll
    for (int n = 0; n < 2; ++n) {
      const int j = (nw * 2 + n) * 16 + (l & 15);
      bf16x8 yb = *(const bf16x8*)(s0b + (size_t)j * 128 + ko);
      acc[n] = __builtin_amdgcn_mfma_f32_16x16x32_bf16(xa, yb, acc[n], 0, 0, 0);
    }
  }

  // g = (O_inter + O_intra) * sigmoid(gate); per-row sum of squares.
  __shared__ float ssh[2][32];    // [n-half][row]
  float gval[2][4];
  float ssr[4];
#pragma unroll
  for (int r = 0; r < 4; ++r) {
    ssr[r] = 0.f;
    const int row = mw * 16 + (l >> 4) * 4 + r;
    const size_t rowg = ((size_t)(b * NSEQ + c * CHUNK + row)) * DMODEL + c0;
#pragma unroll
    for (int n = 0; n < 2; ++n) {
      const int col = (nw * 2 + n) * 16 + (l & 15);
      const float o = acc[n][r] + bf2f(ob[rowg + col]);
      const float gv = bf2f(gate[rowg + col]);
      const float g = o / (1.f + expf(-gv));
      gval[n][r] = g;
      ssr[r] = fmaf(g, g, ssr[r]);
    }
  }
#pragma unroll
  for (int r = 0; r < 4; ++r) {
    ssr[r] += __shfl_xor(ssr[r], 1);
    ssr[r] += __shfl_xor(ssr[r], 2);
    ssr[r] += __shfl_xor(ssr[r], 4);
    ssr[r] += __shfl_xor(ssr[r], 8);
  }
  if ((l & 15) == 0) {
#pragma unroll
    for (int r = 0; r < 4; ++r)
      ssh[nw][mw * 16 + (l >> 4) * 4 + r] = ssr[r];
  }
  __syncthreads();
#pragma unroll
  for (int r = 0; r < 4; ++r) {
    const int row = mw * 16 + (l >> 4) * 4 + r;
    const float ss = ssr[r] + ssh[nw ^ 1][row];
    const float inv = 1.0f / sqrtf(ss * (1.0f / 64.0f) + 1e-6f);
    const size_t rowg = ((size_t)(b * NSEQ + c * CHUNK + row)) * DMODEL + c0;
#pragma unroll
    for (int n = 0; n < 2; ++n) {
      const int col = (nw * 2 + n) * 16 + (l & 15);
      outb[rowg + col] = f2bf(gval[n][r] * inv * norm_w[c0 + col]);
    }
  }
}

// ---------------------------------------------------------------------------
// Fallback sequential scan (f32 path, used only if ws too small).
// ---------------------------------------------------------------------------
__global__ __launch_bounds__(256) void scan_kernel(const float* __restrict__ qb,
                                                   const float* __restrict__ kb,
                                                   const float* __restrict__ vb,
                                                   float* __restrict__ ob) {
  const int bh = blockIdx.x;
  const int b = bh >> 4;
  const int h = bh & 15;
  const int c0 = h * HD;

  __shared__ float sk[64][64];
  __shared__ float sq[64][64];
  __shared__ float sv[64][64];
  __shared__ float kh[128];
  __shared__ float qph[128];
  __shared__ float vsh[64];
  __shared__ float opart[4][64];

  const int tid = threadIdx.x;
  const int lane = tid & 63;
  const int w = tid >> 6;
  const int e0 = w * 32;

  float T[32];
#pragma unroll
  for (int i = 0; i < 32; ++i) T[i] = 0.f;

  float zrun = 1.0f;
  float theta_v = 0.f;
  if (tid < 64) theta_v = expf(-2.0f * (float)(c0 + tid) * (1.0f / 1024.0f) * LN_BASE);

  for (int t0 = 0; t0 < NSEQ; t0 += 64) {
    __syncthreads();
    for (int idx = tid; idx < 64 * 64; idx += 256) {
      const int tl = idx >> 6;
      const int dd = idx & 63;
      const size_t g = ((size_t)(b * NSEQ + t0 + tl)) * DMODEL + c0 + dd;
      sk[tl][dd] = kb[g];
      sq[tl][dd] = qb[g];
      sv[tl][dd] = vb[g];
    }
    __syncthreads();

    for (int tl = 0; tl < 64; ++tl) {
      const int t = t0 + tl;
      if (tid < 64) {
        const int dd = tid;
        const float kr = sk[tl][dd];
        const float ek = expf(kr);
        zrun += ek;
        const float inv = 1.0f / zrun;
        float cs_, sn;
        fast_sincos((float)t * theta_v, &sn, &cs_);
        const float qv = sq[tl][dd];
        kh[dd] = ek * cs_;
        kh[64 + dd] = ek * sn;
        qph[dd] = qv * cs_ * inv;
        qph[64 + dd] = qv * sn * inv;
        vsh[dd] = sv[tl][dd];
      }
      __syncthreads();

      const float vj = vsh[lane];
      float accj = 0.f;
#pragma unroll
      for (int i = 0; i < 32; ++i) {
        T[i] = fmaf(kh[e0 + i], vj, T[i]);
        accj = fmaf(qph[e0 + i], T[i], accj);
      }
      opart[w][lane] = accj;
      __syncthreads();

      if (tid < 64) {
        const float o = opart[0][tid] + opart[1][tid] + opart[2][tid] + opart[3][tid];
        ob[((size_t)(b * NSEQ + t)) * DMODEL + c0 + tid] = o;
      }
    }
  }
}

// ---------------------------------------------------------------------------
// Gated group-RMSNorm, f32 (fallback path only).
// ---------------------------------------------------------------------------
__global__ __launch_bounds__(256) void gated_rmsnorm_f32(
    const float* __restrict__ o, const float* __restrict__ gate,
    const float* __restrict__ norm_w, float* __restrict__ outf) {
  const int gidx = blockIdx.x * 4 + (threadIdx.x >> 6);
  const int lane = threadIdx.x & 63;
  const size_t base = (size_t)gidx * 64 + lane;
  const float ov = o[base];
  const float gv = gate[base];
  const float g = ov / (1.f + expf(-gv));
  float ss = g * g;
#pragma unroll
  for (int off = 32; off; off >>= 1) ss += __shfl_xor(ss, off);
  const float rms = sqrtf(ss * (1.0f / 64.0f) + 1e-6f);
  const int cch = (gidx & 15) * 64 + lane;
  outf[base] = g / rms * norm_w[cch];
}

// ---------------------------------------------------------------------------
extern "C" void kernel_launch(void* const* d_in, const int* in_sizes, int n_in,
                              void* d_out, int out_size, void* d_ws, size_t ws_size,
                              hipStream_t stream) {
  const float* x      = (const float*)d_in[0];
  const float* wq     = (const float*)d_in[1];
  const float* wk     = (const float*)d_in[2];
  const float* wv     = (const float*)d_in[3];
  const float* wo     = (const float*)d_in[4];
  const float* wg1    = (const float*)d_in[5];
  const float* wg2    = (const float*)d_in[6];
  const float* norm_w = (const float*)d_in[7];
  float* out = (float*)d_out;

  const int M = BATCH * NSEQ;            // 4096
  const size_t SZ = (size_t)M * DMODEL;  // 4,194,304 elements
  const size_t WSZ = (size_t)DMODEL * DMODEL;  // 1M

  // fp32 region (regions sized f32; bf16 views alias the same memory)
  float* qbuf = (float*)d_ws;
  float* kbuf = qbuf + SZ;
  float* vbuf = kbuf + SZ;
  float* obuf = vbuf + SZ;
  float* gbuf = obuf + SZ;
  float* g1   = gbuf + SZ;                                  // M*64
  float* part = g1 + (size_t)M * HD;                        // 2*64*1024
  float* zoff = part + (size_t)BATCH * NCH * DMODEL;
  float* qpb  = zoff + (size_t)BATCH * NCH * DMODEL;
  float* Gb   = qpb + (size_t)BATCH * NH * NCH * CHUNK * 128;
  float* f32_end = Gb + (size_t)BATCH * NH * NCH * 8192;

  // bf16 region (ushort)
  unsigned short* xbf   = (unsigned short*)f32_end;
  unsigned short* wAll  = xbf + SZ;          // [wqT|wkT|wvT] 3072x1024
  unsigned short* wqT   = wAll;
  unsigned short* wkT   = wAll + WSZ;
  unsigned short* wvT   = wAll + 2 * WSZ;
  unsigned short* wg1T  = wAll + 3 * WSZ;            // 64x1024
  unsigned short* wg2T  = wg1T + (size_t)64 * DMODEL; // 1024x64
  unsigned short* g1b   = wg2T + (size_t)64 * DMODEL; // 4096x64
  unsigned short* woT   = wAll + 4 * WSZ;
  unsigned short* nrmbf = woT + WSZ;
  unsigned short* u16_end = nrmbf + SZ;

  const size_t need_full = (size_t)((char*)u16_end - (char*)d_ws);

  // bf16 views (full path)
  unsigned short* qbuf16 = (unsigned short*)qbuf;
  unsigned short* kbuf16 = (unsigned short*)kbuf;
  unsigned short* vbuf16 = (unsigned short*)vbuf;
  unsigned short* obuf16 = (unsigned short*)obuf;
  unsigned short* gbuf16 = (unsigned short*)gbuf;
  unsigned short* qpb16  = (unsigned short*)qpb;
  unsigned short* Gb16   = (unsigned short*)Gb;

  dim3 blk(256);
  dim3 grid_d((DMODEL + 127) / 128, (M + 127) / 128);
  dim3 grid_g1(1, (M + 127) / 128);

  const bool full_ok = ws_size >= need_full;

  if (full_ok) {
    // ONE batched kernel: 4 weight transposes + x conversion + wg1T + wg2T.
    transpose_cvt7<<<dim3(32, 32, 7), blk, 0, stream>>>(
        wq, wk, wv, wo, x, wg1, wg2, wqT, wkT, wvT, woT, xbf, wg1T, wg2T);
    // Low-rank gate path: g1 = x @ wg1 (N=64), gate = g1 @ wg2 (K=64).
    gemm_bf16_g1<<<dim3(M / 16), blk, 0, stream>>>(xbf, wg1T, g1b);
    gemm_bf16_gate<<<dim3((M / 32) * (DMODEL / 128)), blk, 0, stream>>>(
        g1b, wg2T, gbuf16, M, DMODEL, 64);
    // Fused projections: 4096x3072x1024, bf16 outputs, BM=128 -> 768 blocks.
    gemm_bf16_fused<<<dim3((M / 128) * (3 * DMODEL / 128)), blk, 0, stream>>>(
        xbf, wAll, qbuf16, kbuf16, vbuf16, M, 3 * DMODEL, DMODEL);

    chunk_partial<<<dim3(BATCH * NCH * 4), blk, 0, stream>>>(kbuf16, part);
    chunk_zoff<<<dim3(8), blk, 0, stream>>>(part, zoff);
    chunk_attn<<<dim3(BATCH * NH * NCH), blk, 0, stream>>>(qbuf16, kbuf16, vbuf16,
                                                           zoff, qpb16, Gb16, obuf16);
    chunk_prefix<<<dim3(BATCH * NH * 8192 / 512), blk, 0, stream>>>(Gb16);
    chunk_inter_norm<<<dim3(BATCH * NH * NCH), blk, 0, stream>>>(
        qpb16, Gb16, obuf16, gbuf16, norm_w, nrmbf);

    // wo GEMM: BM=32 -> 1024 blocks (4/CU).
    gemm_bf16_wo<<<dim3((M / 32) * (DMODEL / 128)), blk, 0, stream>>>(
        nrmbf, woT, out, M, DMODEL, DMODEL);
  } else {
    // f32 fallback: separate buffers, sequential scan.
    gemm_f32<1><<<grid_d, blk, 0, stream>>>(x, wq, qbuf, M, DMODEL, DMODEL);
    gemm_f32<0><<<grid_d, blk, 0, stream>>>(x, wk, kbuf, M, DMODEL, DMODEL);
    gemm_f32<0><<<grid_d, blk, 0, stream>>>(x, wv, vbuf, M, DMODEL, DMODEL);
    gemm_f32<0><<<grid_g1, blk, 0, stream>>>(x, wg1, g1, M, HD, DMODEL);
    gemm_f32<0><<<grid_d, blk, 0, stream>>>(g1, wg2, gbuf, M, DMODEL, HD);
    scan_kernel<<<dim3(BATCH * NH), blk, 0, stream>>>(qbuf, kbuf, vbuf, obuf);
    float* nrm = kbuf;
    gated_rmsnorm_f32<<<dim3(M * NH / 4), blk, 0, stream>>>(obuf, gbuf, norm_w, nrm);
    gemm_f32<0><<<grid_d, blk, 0, stream>>>(nrm, wo, out, M, DMODEL, DMODEL);
  }
}

// Round 33
// 129.395 us; speedup vs baseline: 1.0492x; 1.0287x over previous
//
#include <hip/hip_runtime.h>
#include <math.h>

#define NH 16
#define HD 64
#define DMODEL 1024
#define NSEQ 2048
#define BATCH 2
#define CHUNK 32
#define NCH (NSEQ / CHUNK)            // 64 chunks
#define LN_BASE 9.210340371976184f    // ln(10000)

typedef __attribute__((ext_vector_type(8))) short bf16x8;
typedef __attribute__((ext_vector_type(8))) unsigned short u16x8;
typedef __attribute__((ext_vector_type(4))) float f32x4;

__device__ __forceinline__ unsigned short f2bf(float f) {
  union { float f; unsigned int u; } v; v.f = f;
  unsigned int u = v.u;
  unsigned int r = u + 0x7FFFu + ((u >> 16) & 1u);   // RNE
  return (unsigned short)(r >> 16);
}
__device__ __forceinline__ float bf2f(unsigned short u) {
  union { unsigned int u; float f; } v; v.u = ((unsigned int)u) << 16;
  return v.f;
}

// Fast range-reduced sincos (HW v_sin/v_cos after reduction to one revolution).
__device__ __forceinline__ void fast_sincos(float ang, float* s, float* c) {
  const float INV2PI = 0.15915494309189535f;
  const float TWOPI  = 6.283185307179586f;
  float rev = ang * INV2PI;
  rev = rev - floorf(rev);          // [0,1)
  float ar = rev * TWOPI;
  *s = __sinf(ar);
  *c = __cosf(ar);
}

// Async global->LDS, 16B per lane (dest = wave-uniform base + lane*16).
__device__ __forceinline__ void gload_lds16(const unsigned short* g,
                                            unsigned short* l) {
  __builtin_amdgcn_global_load_lds(
      (const __attribute__((address_space(1))) void*)g,
      (__attribute__((address_space(3))) void*)l, 16, 0, 0);
}

// ---------------------------------------------------------------------------
// Batched transposes + x conversion:
//   z=0..3 : [1024][1024] f32 -> bf16^T   (wq wk wv wo)
//   z=4    : x f32 -> bf16 linear
//   z=5    : wg1 [1024][64]  -> wg1T [64][1024]  (only blockIdx.x<2 active)
//   z=6    : wg2 [64][1024]  -> wg2T [1024][64]  (only blockIdx.y<2 active)
// ---------------------------------------------------------------------------
__global__ __launch_bounds__(256) void transpose_cvt7(
    const float* __restrict__ s0, const float* __restrict__ s1,
    const float* __restrict__ s2, const float* __restrict__ s3,
    const float* __restrict__ xs, const float* __restrict__ wg1,
    const float* __restrict__ wg2,
    unsigned short* __restrict__ d0, unsigned short* __restrict__ d1,
    unsigned short* __restrict__ d2, unsigned short* __restrict__ d3,
    unsigned short* __restrict__ xd, unsigned short* __restrict__ wg1T,
    unsigned short* __restrict__ wg2T) {
  const int z = blockIdx.z;
  if (z == 4) {
    const int lin = blockIdx.y * 32 + blockIdx.x;   // 0..1023
    const size_t base = (size_t)lin * 4096 + threadIdx.x * 4;
#pragma unroll
    for (int r = 0; r < 4; ++r) {
      float4 v = *(const float4*)(xs + base + r * 1024);
      unsigned short* o = xd + base + r * 1024;
      o[0] = f2bf(v.x); o[1] = f2bf(v.y); o[2] = f2bf(v.z); o[3] = f2bf(v.w);
    }
    return;
  }
  const float* in;
  unsigned short* out;
  int R, Cn;
  if (z < 4) {
    in = (z == 0) ? s0 : (z == 1) ? s1 : (z == 2) ? s2 : s3;
    out = (z == 0) ? d0 : (z == 1) ? d1 : (z == 2) ? d2 : d3;
    R = DMODEL; Cn = DMODEL;
  } else if (z == 5) {
    if (blockIdx.x >= 2) return;     // Cn=64 -> 2 col-tiles
    in = wg1; out = wg1T; R = DMODEL; Cn = 64;
  } else {
    if (blockIdx.y >= 2) return;     // R=64 -> 2 row-tiles
    in = wg2; out = wg2T; R = 64; Cn = DMODEL;
  }
  __shared__ float tl[32][33];
  const int t = threadIdx.x;
  const int ci = t & 31, ri = t >> 5;   // ri in 0..7
  const int br = blockIdx.y * 32, bc = blockIdx.x * 32;
#pragma unroll
  for (int rr = 0; rr < 4; ++rr)
    tl[ri + rr * 8][ci] = in[(size_t)(br + ri + rr * 8) * Cn + bc + ci];
  __syncthreads();
#pragma unroll
  for (int rr = 0; rr < 4; ++rr) {
    const int orow = bc + ri + rr * 8;   // output row = input col
    const int ocol = br + ci;            // output col = input row
    out[(size_t)orow * R + ocol] = f2bf(tl[ci][ri + rr * 8]);
  }
}

// ---------------------------------------------------------------------------
// g1 = x[4096][1024] @ wg1T[64][1024]^T -> bf16 [4096][64]  (low-rank gate
// step 1).  BM=16, N=64, BK=64 -> 256 blocks (1/CU).
// ---------------------------------------------------------------------------
__global__ __launch_bounds__(256) void gemm_bf16_g1(
    const unsigned short* __restrict__ A, const unsigned short* __restrict__ Bt,
    unsigned short* __restrict__ C) {
  __shared__ unsigned short As[16][64];    // 2 KB
  __shared__ unsigned short Bs[64][64];    // 8 KB
  const int tid = threadIdx.x;
  const int l = tid & 63;
  const int w = tid >> 6;
  const int bm = blockIdx.x * 16;
  const int K = DMODEL;

  const int lrow = l >> 3;
  const int cd = l & 7;
  const int cl = cd ^ lrow;

  f32x4 acc = (f32x4){0.f, 0.f, 0.f, 0.f};

  for (int k0 = 0; k0 < K; k0 += 64) {
    __syncthreads();
    if (w < 2) {                        // A: wave w stages rows [w*8, w*8+8)
      const int row = w * 8 + lrow;
      unsigned short* la = (unsigned short*)As + (w * 8) * 64 + l * 8;
      gload_lds16(A + (size_t)(bm + row) * K + k0 + cl * 8, la);
    }
    {                                   // B: wave w stages rows [w*16, w*16+16)
#pragma unroll
      for (int c = 0; c < 2; ++c) {
        const int row = w * 16 + c * 8 + lrow;
        unsigned short* lb = (unsigned short*)Bs + (w * 16 + c * 8) * 64 + l * 8;
        gload_lds16(Bt + (size_t)row * K + k0 + cl * 8, lb);
      }
    }
    __syncthreads();

#pragma unroll
    for (int ks = 0; ks < 2; ++ks) {
      bf16x8 af, bfr;
      {
        const int r = l & 15;
        const int phys = (ks * 4 + (l >> 4)) ^ (r & 7);
        af = *(const bf16x8*)&As[r][phys * 8];
      }
      {
        const int r = w * 16 + (l & 15);
        const int phys = (ks * 4 + (l >> 4)) ^ (r & 7);
        bfr = *(const bf16x8*)&Bs[r][phys * 8];
      }
      acc = __builtin_amdgcn_mfma_f32_16x16x32_bf16(af, bfr, acc, 0, 0, 0);
    }
  }

  {
    const int row0 = bm + (l >> 4) * 4;
    const int col = w * 16 + (l & 15);
#pragma unroll
    for (int r = 0; r < 4; ++r)
      C[(size_t)(row0 + r) * 64 + col] = f2bf(acc[r]);
  }
}

// ---------------------------------------------------------------------------
// bf16 MFMA GEMM, fused 3-output (round-31: Ntot=3072 -> 768 blocks).
// BM=128 single buffer (round-28/30 verified optimum).  2D XCD regions:
// 768 = 8 XCD x 96; region = 8 bm x 12 bn.  Bands -> B0..B2, silu on B0.
// ---------------------------------------------------------------------------
__global__ __launch_bounds__(256, 4) void gemm_bf16_fused(
    const unsigned short* __restrict__ A, const unsigned short* __restrict__ Bt,
    unsigned short* __restrict__ B0, unsigned short* __restrict__ B1,
    unsigned short* __restrict__ B2,
    int M, int Ntot, int K) {
  __shared__ unsigned short As[128][64];   // 16 KB
  __shared__ unsigned short Bs[128][64];   // 16 KB
  const int tid = threadIdx.x;
  const int l = tid & 63;
  const int w = tid >> 6;
  const int wr = (w >> 1) * 64;
  const int wc = (w & 1) * 64;

  const int orig = blockIdx.x;
  const int xcd = orig & 7;
  const int idx = orig >> 3;               // 0..95
  const int bm = ((xcd >> 1) * 8 + (idx & 7)) * 128;
  const int bn = ((xcd & 1) * 12 + (idx >> 3)) * 128;

  const int lrow = l >> 3;                 // 0..7 row within call
  const int cd = l & 7;                    // dest 16B chunk
  const int cl = cd ^ lrow;                // logical chunk fetched (row&7==lrow)

  f32x4 acc[4][4];
#pragma unroll
  for (int m = 0; m < 4; ++m)
#pragma unroll
    for (int n = 0; n < 4; ++n) acc[m][n] = (f32x4){0.f, 0.f, 0.f, 0.f};

  for (int k0 = 0; k0 < K; k0 += 64) {
    __syncthreads();   // previous iteration's ds_reads complete
#pragma unroll
    for (int c = 0; c < 4; ++c) {       // A: wave stages rows [w*32, w*32+32)
      const int row = w * 32 + c * 8 + lrow;
      unsigned short* la = (unsigned short*)As + (w * 32 + c * 8) * 64 + l * 8;
      gload_lds16(A + (size_t)(bm + row) * K + k0 + cl * 8, la);
    }
#pragma unroll
    for (int c = 0; c < 4; ++c) {       // B: wave stages rows [w*32, w*32+32)
      const int row = w * 32 + c * 8 + lrow;
      unsigned short* lb = (unsigned short*)Bs + (w * 32 + c * 8) * 64 + l * 8;
      gload_lds16(Bt + (size_t)(bn + row) * K + k0 + cl * 8, lb);
    }
    __syncthreads();   // vmcnt(0) drained before barrier -> tiles ready

#pragma unroll
    for (int ks = 0; ks < 2; ++ks) {
      bf16x8 af[4], bfr[4];
#pragma unroll
      for (int m = 0; m < 4; ++m) {
        const int r = wr + m * 16 + (l & 15);
        const int phys = (ks * 4 + (l >> 4)) ^ (r & 7);
        af[m] = *(const bf16x8*)&As[r][phys * 8];
      }
#pragma unroll
      for (int n = 0; n < 4; ++n) {
        const int r = wc + n * 16 + (l & 15);
        const int phys = (ks * 4 + (l >> 4)) ^ (r & 7);
        bfr[n] = *(const bf16x8*)&Bs[r][phys * 8];
      }
#pragma unroll
      for (int m = 0; m < 4; ++m)
#pragma unroll
        for (int n = 0; n < 4; ++n)
          acc[m][n] = __builtin_amdgcn_mfma_f32_16x16x32_bf16(af[m], bfr[n], acc[m][n], 0, 0, 0);
    }
  }

#pragma unroll
  for (int m = 0; m < 4; ++m) {
    const int row0 = bm + wr + m * 16 + (l >> 4) * 4;
#pragma unroll
    for (int n = 0; n < 4; ++n) {
      const int colw = wc + n * 16 + (l & 15);
#pragma unroll
      for (int r = 0; r < 4; ++r) {
        float x = acc[m][n][r];
        const int nb = bn >> 10;
        unsigned short* Bb = (nb == 0) ? B0 : (nb == 1) ? B1 : B2;
        const int col = (bn & 1023) + colw;
        if (nb == 0) x = x / (1.f + expf(-x));
        Bb[(size_t)(row0 + r) * DMODEL + col] = f2bf(x);
      }
    }
  }
}

// ---------------------------------------------------------------------------
// wo GEMM (round-26 verified: BM=32 -> 1024 blocks = 4/CU).  f32 output.
// ---------------------------------------------------------------------------
__global__ __launch_bounds__(256, 6) void gemm_bf16_wo(
    const unsigned short* __restrict__ A, const unsigned short* __restrict__ Bt,
    float* __restrict__ C, int M, int N, int K) {
  __shared__ unsigned short As[32][64];    // 4 KB
  __shared__ unsigned short Bs[128][64];   // 16 KB
  const int tid = threadIdx.x;
  const int l = tid & 63;
  const int w = tid >> 6;
  const int wr = (w >> 1) * 16;            // 0/16
  const int wc = (w & 1) * 64;

  const int nwg = gridDim.x;               // 1024
  const int orig = blockIdx.x;
  const int swz = (orig & 7) * (nwg >> 3) + (orig >> 3);
  const int ntn = N >> 7;                  // 8
  const int bm = (swz / ntn) * 32;
  const int bn = (swz % ntn) * 128;

  const int lrow = l >> 3;
  const int cd = l & 7;
  const int cl = cd ^ lrow;

  f32x4 acc[4];
#pragma unroll
  for (int n = 0; n < 4; ++n) acc[n] = (f32x4){0.f, 0.f, 0.f, 0.f};

  for (int k0 = 0; k0 < K; k0 += 64) {
    __syncthreads();
    {                                   // A: wave stages rows [w*8, w*8+8)
      const int row = w * 8 + lrow;
      unsigned short* la = (unsigned short*)As + (w * 8) * 64 + l * 8;
      gload_lds16(A + (size_t)(bm + row) * K + k0 + cl * 8, la);
    }
#pragma unroll
    for (int c = 0; c < 4; ++c) {       // B: wave stages rows [w*32, w*32+32)
      const int row = w * 32 + c * 8 + lrow;
      unsigned short* lb = (unsigned short*)Bs + (w * 32 + c * 8) * 64 + l * 8;
      gload_lds16(Bt + (size_t)(bn + row) * K + k0 + cl * 8, lb);
    }
    __syncthreads();

#pragma unroll
    for (int ks = 0; ks < 2; ++ks) {
      bf16x8 af, bfr[4];
      {
        const int r = wr + (l & 15);
        const int phys = (ks * 4 + (l >> 4)) ^ (r & 7);
        af = *(const bf16x8*)&As[r][phys * 8];
      }
#pragma unroll
      for (int n = 0; n < 4; ++n) {
        const int r = wc + n * 16 + (l & 15);
        const int phys = (ks * 4 + (l >> 4)) ^ (r & 7);
        bfr[n] = *(const bf16x8*)&Bs[r][phys * 8];
      }
#pragma unroll
      for (int n = 0; n < 4; ++n)
        acc[n] = __builtin_amdgcn_mfma_f32_16x16x32_bf16(af, bfr[n], acc[n], 0, 0, 0);
    }
  }

  {
    const int row0 = bm + wr + (l >> 4) * 4;
#pragma unroll
    for (int n = 0; n < 4; ++n) {
      const int col = bn + wc + n * 16 + (l & 15);
#pragma unroll
      for (int r = 0; r < 4; ++r)
        C[(size_t)(row0 + r) * N + col] = acc[n][r];
    }
  }
}

// ---------------------------------------------------------------------------
// Tiled fp32 GEMM (fallback path only).
// ---------------------------------------------------------------------------
template <int ACT>
__global__ __launch_bounds__(256) void gemm_f32(const float* __restrict__ A,
                                                const float* __restrict__ B,
                                                float* __restrict__ C,
                                                int M, int N, int K) {
  __shared__ __align__(16) float As[16][128];
  __shared__ __align__(16) float Bs[16][128];
  const int tid = threadIdx.x;
  const int tx = tid & 15;
  const int ty = tid >> 4;
  const int bm = blockIdx.y * 128;
  const int bn = blockIdx.x * 128;

  float acc[8][8];
#pragma unroll
  for (int i = 0; i < 8; ++i)
#pragma unroll
    for (int j = 0; j < 8; ++j) acc[i][j] = 0.f;

  for (int k0 = 0; k0 < K; k0 += 16) {
    {
      const int row = tid >> 1;
      const int ko = (tid & 1) * 8;
      const float* src = A + (size_t)(bm + row) * K + k0 + ko;
      float4 a0 = *(const float4*)src;
      float4 a1 = *(const float4*)(src + 4);
      As[ko + 0][row] = a0.x; As[ko + 1][row] = a0.y;
      As[ko + 2][row] = a0.z; As[ko + 3][row] = a0.w;
      As[ko + 4][row] = a1.x; As[ko + 5][row] = a1.y;
      As[ko + 6][row] = a1.z; As[ko + 7][row] = a1.w;
    }
    {
      const int kr = tid >> 4;
      const int no = (tid & 15) * 8;
      float4 b0 = make_float4(0.f, 0.f, 0.f, 0.f);
      float4 b1 = b0;
      if (no < N) {
        const float* src = B + (size_t)(k0 + kr) * N + bn + no;
        b0 = *(const float4*)src;
        b1 = *(const float4*)(src + 4);
      }
      *(float4*)&Bs[kr][no] = b0;
      *(float4*)&Bs[kr][no + 4] = b1;
    }
    __syncthreads();
#pragma unroll
    for (int kk = 0; kk < 16; ++kk) {
      float a[8], b[8];
      *(float4*)&a[0] = *(const float4*)&As[kk][ty * 8];
      *(float4*)&a[4] = *(const float4*)&As[kk][ty * 8 + 4];
      *(float4*)&b[0] = *(const float4*)&Bs[kk][tx * 8];
      *(float4*)&b[4] = *(const float4*)&Bs[kk][tx * 8 + 4];
#pragma unroll
      for (int i = 0; i < 8; ++i)
#pragma unroll
        for (int j = 0; j < 8; ++j) acc[i][j] = fmaf(a[i], b[j], acc[i][j]);
    }
    __syncthreads();
  }

#pragma unroll
  for (int i = 0; i < 8; ++i) {
    const int row = bm + ty * 8 + i;
#pragma unroll
    for (int j = 0; j < 8; j += 4) {
      const int col = bn + tx * 8 + j;
      if (col < N) {
        float4 r;
        float* rv = (float*)&r;
#pragma unroll
        for (int q = 0; q < 4; ++q) {
          float x = acc[i][j + q];
          if (ACT == 1) x = x / (1.f + expf(-x));
          rv[q] = x;
        }
        *(float4*)&C[(size_t)row * N + col] = r;
      }
    }
  }
}

// ---------------------------------------------------------------------------
// Phase P1: per-chunk partial sums of exp(k), per channel.  (bf16 k)
// ---------------------------------------------------------------------------
__global__ __launch_bounds__(256) void chunk_partial(
    const unsigned short* __restrict__ kb, float* __restrict__ partial) {
  const int blk = blockIdx.x;              // 0..511
  const int b = blk >> 8;
  const int rem = blk & 255;
  const int c = rem >> 2;
  const int seg = rem & 3;
  const int ch = seg * 256 + threadIdx.x;
  const unsigned short* base = kb + ((size_t)(b * NSEQ + c * CHUNK)) * DMODEL + ch;
  float acc = 0.f;
  for (int s = 0; s < CHUNK; ++s)
    acc += expf(bf2f(base[(size_t)s * DMODEL]));
  partial[((size_t)(b * NCH + c)) * DMODEL + ch] = acc;
}

// ---------------------------------------------------------------------------
// Phase P2: exclusive chunk prefix (+1 for zeros row).  Load-all then scan.
// ---------------------------------------------------------------------------
__global__ __launch_bounds__(256) void chunk_zoff(const float* __restrict__ partial,
                                                  float* __restrict__ zoff) {
  const int g = blockIdx.x * 256 + threadIdx.x;   // 0..2047
  const int b = g >> 10, dd = g & 1023;
  const size_t base = (size_t)b * NCH * DMODEL + dd;
  float vals[NCH];
#pragma unroll
  for (int c = 0; c < NCH; ++c)
    vals[c] = partial[base + (size_t)c * DMODEL];
  float run = 1.0f;
#pragma unroll
  for (int c = 0; c < NCH; ++c) {
    zoff[base + (size_t)c * DMODEL] = run;
    run += vals[c];
  }
}

// ---------------------------------------------------------------------------
// Main chunk kernel, MFMA version.  grid = 2048 blocks, 4 waves.
// k/v staging vectorized u16x8 (round-32 verified).
// G written TRANSPOSED (G^T[j][e], [64][128] per block) for the MFMA inter.
// ---------------------------------------------------------------------------
__global__ __launch_bounds__(256) void chunk_attn(
    const unsigned short* __restrict__ qb, const unsigned short* __restrict__ kb,
    const unsigned short* __restrict__ vb, const float* __restrict__ zoff,
    unsigned short* __restrict__ qp, unsigned short* __restrict__ G,
    unsigned short* __restrict__ ob) {
  const int bidx = blockIdx.x;
  const int bh = bidx / NCH, c = bidx % NCH;
  const int b = bh >> 4, h = bh & 15;
  const int c0 = h * HD;

  __shared__ float sk[CHUNK][64];                               // 8192 B
  __shared__ float ps[4][64];                                   // 1024 B
  __shared__ __align__(16) unsigned short qplds[CHUNK][136];    // 8704 B
  __shared__ __align__(16) unsigned short khlds[CHUNK][136];    // 8704 B
  __shared__ __align__(16) unsigned short kht[128][40];         // 10240 B
  __shared__ __align__(16) unsigned short vt[64][40];           // 5120 B
  __shared__ __align__(16) unsigned short slds[CHUNK][40];      // 2560 B

  const int tid = threadIdx.x;
  const int l = tid & 63;
  const int w = tid >> 6;

  // stage k (f32 for exp) and v -> VT (bf16 transposed), 16B vector loads:
  // thread tid covers s = tid>>3, channels (tid&7)*8 .. +8.
  {
    const int s = tid >> 3, d0 = (tid & 7) * 8;
    const size_t g = ((size_t)(b * NSEQ + c * CHUNK + s)) * DMODEL + c0 + d0;
    u16x8 kv8 = *(const u16x8*)(kb + g);
    u16x8 vv8 = *(const u16x8*)(vb + g);
#pragma unroll
    for (int q = 0; q < 8; ++q) {
      sk[s][d0 + q] = bf2f(kv8[q]);
      vt[d0 + q][s] = vv8[q];
    }
  }
  __syncthreads();

  // ---- phase A: Z cumsum + build QP/KH/KHT (thread = channel dd, 8 s) ----
  const int dd = l;
  const int wq_ = w;
  {
    float a = 0.f;
#pragma unroll
    for (int i = 0; i < CHUNK / 4; ++i) a += expf(sk[wq_ * (CHUNK / 4) + i][dd]);
    ps[wq_][dd] = a;
  }
  __syncthreads();
  {
    float z = zoff[((size_t)(b * NCH + c)) * DMODEL + c0 + dd];
    for (int q2 = 0; q2 < wq_; ++q2) z += ps[q2][dd];
    const float theta = expf(-2.0f * (float)(c0 + dd) * (1.0f / 1024.0f) * LN_BASE);
#pragma unroll 2
    for (int i = 0; i < CHUNK / 4; ++i) {
      const int s = wq_ * (CHUNK / 4) + i;
      const int t = c * CHUNK + s;
      const float ek = expf(sk[s][dd]);
      z += ek;
      float sn, cs_;
      fast_sincos((float)t * theta, &sn, &cs_);
      const float qv = bf2f(qb[((size_t)(b * NSEQ + t)) * DMODEL + c0 + dd]);
      const float inv = 1.0f / z;
      const unsigned short kcb = f2bf(ek * cs_);
      const unsigned short ksb = f2bf(ek * sn);
      const unsigned short qcb = f2bf(qv * cs_ * inv);
      const unsigned short qsb = f2bf(qv * sn * inv);
      khlds[s][dd] = kcb;
      khlds[s][64 + dd] = ksb;
      kht[dd][s] = kcb;
      kht[64 + dd][s] = ksb;
      qplds[s][dd] = qcb;
      qplds[s][64 + dd] = qsb;
      unsigned short* qpo = qp + ((size_t)bidx * CHUNK + s) * 128;
      qpo[dd] = qcb;
      qpo[64 + dd] = qsb;
    }
  }
  __syncthreads();

  // ---- score: S = QP(32x128) @ KH^T, causal-masked, -> slds bf16 ----
  {
    const int mw = w >> 1, nw = w & 1;
    f32x4 sd = (f32x4){0.f, 0.f, 0.f, 0.f};
#pragma unroll
    for (int ks = 0; ks < 4; ++ks) {
      bf16x8 aq = *(const bf16x8*)&qplds[mw * 16 + (l & 15)][(l >> 4) * 8 + ks * 32];
      bf16x8 bk = *(const bf16x8*)&khlds[nw * 16 + (l & 15)][(l >> 4) * 8 + ks * 32];
      sd = __builtin_amdgcn_mfma_f32_16x16x32_bf16(aq, bk, sd, 0, 0, 0);
    }
    const int trow = mw * 16 + (l >> 4) * 4;
    const int scol = nw * 16 + (l & 15);
#pragma unroll
    for (int r = 0; r < 4; ++r) {
      const float v = (scol <= trow + r) ? sd[r] : 0.f;
      slds[trow + r][scol] = f2bf(v);
    }
  }

  // ---- G^T = (KHT(128x32) @ V(32x64))^T -> global bf16 [64][128] ----
  {
    unsigned short* go = G + (size_t)bidx * 8192;
    const bf16x8 bv = *(const bf16x8*)&vt[w * 16 + (l & 15)][(l >> 4) * 8];
    const int jc = w * 16 + (l & 15);
#pragma unroll
    for (int et = 0; et < 8; ++et) {
      bf16x8 ak = *(const bf16x8*)&kht[et * 16 + (l & 15)][(l >> 4) * 8];
      f32x4 gd = (f32x4){0.f, 0.f, 0.f, 0.f};
      gd = __builtin_amdgcn_mfma_f32_16x16x32_bf16(ak, bv, gd, 0, 0, 0);
      const int e0r = et * 16 + (l >> 4) * 4;
      unsigned long long pk =
          (unsigned long long)f2bf(gd[0])
        | ((unsigned long long)f2bf(gd[1]) << 16)
        | ((unsigned long long)f2bf(gd[2]) << 32)
        | ((unsigned long long)f2bf(gd[3]) << 48);
      *(unsigned long long*)(go + (size_t)jc * 128 + e0r) = pk;
    }
  }
  __syncthreads();   // slds complete before O phase

  // ---- O_intra = S(32x32) @ V(32x64) -> ob bf16 ----
  {
    const bf16x8 bv = *(const bf16x8*)&vt[w * 16 + (l & 15)][(l >> 4) * 8];
    const int jc = w * 16 + (l & 15);
#pragma unroll
    for (int tt = 0; tt < 2; ++tt) {
      bf16x8 as = *(const bf16x8*)&slds[tt * 16 + (l & 15)][(l >> 4) * 8];
      f32x4 od = (f32x4){0.f, 0.f, 0.f, 0.f};
      od = __builtin_amdgcn_mfma_f32_16x16x32_bf16(as, bv, od, 0, 0, 0);
      const int trow = tt * 16 + (l >> 4) * 4;
#pragma unroll
      for (int r = 0; r < 4; ++r)
        ob[((size_t)(b * NSEQ + c * CHUNK + trow + r)) * DMODEL + c0 + jc] = f2bf(od[r]);
    }
  }
}

// ---------------------------------------------------------------------------
// Phase P3: exclusive prefix of G over chunks (in place; load-all then scan).
// ---------------------------------------------------------------------------
__global__ __launch_bounds__(256) void chunk_prefix(unsigned short* __restrict__ G) {
  const int g = blockIdx.x * 256 + threadIdx.x;   // 0 .. 32*4096-1
  const int bh = g >> 12;                          // 4096 pairs per bh
  const int e2 = (g & 4095) * 2;
  unsigned int* base = (unsigned int*)(G + (size_t)bh * NCH * 8192 + e2);
  unsigned int vals[NCH];
#pragma unroll
  for (int c = 0; c < NCH; ++c)
    vals[c] = base[(size_t)c * 4096];
  float run0 = 0.f, run1 = 0.f;
#pragma unroll
  for (int c = 0; c < NCH; ++c) {
    base[(size_t)c * 4096] =
        (unsigned int)f2bf(run0) | ((unsigned int)f2bf(run1) << 16);
    run0 += bf2f((unsigned short)(vals[c] & 0xFFFFu));
    run1 += bf2f((unsigned short)(vals[c] >> 16));
  }
}

// ---------------------------------------------------------------------------
// Inter-chunk + fused gated group-RMSNorm, MFMA version.  Round-33: gate
// computed IN-KERNEL via MFMA (gate = g1 @ wg2, K=64) — eliminates the
// separate gate GEMM, its 16.8 MB write and 16.8 MB re-read.  The wave's
// (mw,nw) 1x2-tile layout matches the verified fragment template exactly:
// A-frag = g1 row (global row), B-frag = wg2T row (gate col), output
// position == acc[n][r] mapping, so gacc[n][r] replaces the gate load.
// ---------------------------------------------------------------------------
__global__ __launch_bounds__(256) void chunk_inter_norm(
    const unsigned short* __restrict__ qp, const unsigned short* __restrict__ S0t,
    const unsigned short* __restrict__ ob, const unsigned short* __restrict__ g1,
    const unsigned short* __restrict__ wg2T,
    const float* __restrict__ norm_w, unsigned short* __restrict__ outb) {
  const int bidx = blockIdx.x;
  const int bh = bidx / NCH, c = bidx % NCH;
  const int b = bh >> 4, h = bh & 15;
  const int c0 = h * HD;

  const int tid = threadIdx.x;
  const int l = tid & 63;
  const int w = tid >> 6;
  const int mw = w >> 1;          // m-tile: rows mw*16..+16
  const int nw = w & 1;           // n-half: cols nw*32..+32 (n tiles 2nw,2nw+1)

  const unsigned short* qpb = qp + (size_t)bidx * CHUNK * 128;   // [32][128]
  const unsigned short* s0b = S0t + (size_t)bidx * 8192;         // [64][128]

  // O_inter = QP(32x128) @ S0t^T
  f32x4 acc[2];
  acc[0] = (f32x4){0.f, 0.f, 0.f, 0.f};
  acc[1] = (f32x4){0.f, 0.f, 0.f, 0.f};
#pragma unroll
  for (int ks = 0; ks < 4; ++ks) {
    const int ko = ks * 32 + (l >> 4) * 8;
    bf16x8 xa = *(const bf16x8*)(qpb + (size_t)(mw * 16 + (l & 15)) * 128 + ko);
#pragma unroll
    for (int n = 0; n < 2; ++n) {
      const int j = (nw * 2 + n) * 16 + (l & 15);
      bf16x8 yb = *(const bf16x8*)(s0b + (size_t)j * 128 + ko);
      acc[n] = __builtin_amdgcn_mfma_f32_16x16x32_bf16(xa, yb, acc[n], 0, 0, 0);
    }
  }

  // gate tile = g1(32x64) @ wg2T^T (K=64), same fragment template.
  f32x4 gacc[2];
  gacc[0] = (f32x4){0.f, 0.f, 0.f, 0.f};
  gacc[1] = (f32x4){0.f, 0.f, 0.f, 0.f};
  {
    const size_t growg =
        ((size_t)(b * NSEQ + c * CHUNK + mw * 16 + (l & 15))) * 64;
#pragma unroll
    for (int ks = 0; ks < 2; ++ks) {
      const int ko = ks * 32 + (l >> 4) * 8;
      bf16x8 ga = *(const bf16x8*)(g1 + growg + ko);
#pragma unroll
      for (int n = 0; n < 2; ++n) {
        const int col = c0 + (nw * 2 + n) * 16 + (l & 15);
        bf16x8 gb = *(const bf16x8*)(wg2T + (size_t)col * 64 + ko);
        gacc[n] = __builtin_amdgcn_mfma_f32_16x16x32_bf16(ga, gb, gacc[n], 0, 0, 0);
      }
    }
  }

  // g = (O_inter + O_intra) * sigmoid(gate); per-row sum of squares.
  __shared__ float ssh[2][32];    // [n-half][row]
  float gval[2][4];
  float ssr[4];
#pragma unroll
  for (int r = 0; r < 4; ++r) {
    ssr[r] = 0.f;
    const int row = mw * 16 + (l >> 4) * 4 + r;
    const size_t rowg = ((size_t)(b * NSEQ + c * CHUNK + row)) * DMODEL + c0;
#pragma unroll
    for (int n = 0; n < 2; ++n) {
      const int col = (nw * 2 + n) * 16 + (l & 15);
      const float o = acc[n][r] + bf2f(ob[rowg + col]);
      const float gv = gacc[n][r];
      const float g = o / (1.f + expf(-gv));
      gval[n][r] = g;
      ssr[r] = fmaf(g, g, ssr[r]);
    }
  }
#pragma unroll
  for (int r = 0; r < 4; ++r) {
    ssr[r] += __shfl_xor(ssr[r], 1);
    ssr[r] += __shfl_xor(ssr[r], 2);
    ssr[r] += __shfl_xor(ssr[r], 4);
    ssr[r] += __shfl_xor(ssr[r], 8);
  }
  if ((l & 15) == 0) {
#pragma unroll
    for (int r = 0; r < 4; ++r)
      ssh[nw][mw * 16 + (l >> 4) * 4 + r] = ssr[r];
  }
  __syncthreads();
#pragma unroll
  for (int r = 0; r < 4; ++r) {
    const int row = mw * 16 + (l >> 4) * 4 + r;
    const float ss = ssr[r] + ssh[nw ^ 1][row];
    const float inv = 1.0f / sqrtf(ss * (1.0f / 64.0f) + 1e-6f);
    const size_t rowg = ((size_t)(b * NSEQ + c * CHUNK + row)) * DMODEL + c0;
#pragma unroll
    for (int n = 0; n < 2; ++n) {
      const int col = (nw * 2 + n) * 16 + (l & 15);
      outb[rowg + col] = f2bf(gval[n][r] * inv * norm_w[c0 + col]);
    }
  }
}

// ---------------------------------------------------------------------------
// Fallback sequential scan (f32 path, used only if ws too small).
// ---------------------------------------------------------------------------
__global__ __launch_bounds__(256) void scan_kernel(const float* __restrict__ qb,
                                                   const float* __restrict__ kb,
                                                   const float* __restrict__ vb,
                                                   float* __restrict__ ob) {
  const int bh = blockIdx.x;
  const int b = bh >> 4;
  const int h = bh & 15;
  const int c0 = h * HD;

  __shared__ float sk[64][64];
  __shared__ float sq[64][64];
  __shared__ float sv[64][64];
  __shared__ float kh[128];
  __shared__ float qph[128];
  __shared__ float vsh[64];
  __shared__ float opart[4][64];

  const int tid = threadIdx.x;
  const int lane = tid & 63;
  const int w = tid >> 6;
  const int e0 = w * 32;

  float T[32];
#pragma unroll
  for (int i = 0; i < 32; ++i) T[i] = 0.f;

  float zrun = 1.0f;
  float theta_v = 0.f;
  if (tid < 64) theta_v = expf(-2.0f * (float)(c0 + tid) * (1.0f / 1024.0f) * LN_BASE);

  for (int t0 = 0; t0 < NSEQ; t0 += 64) {
    __syncthreads();
    for (int idx = tid; idx < 64 * 64; idx += 256) {
      const int tl = idx >> 6;
      const int dd = idx & 63;
      const size_t g = ((size_t)(b * NSEQ + t0 + tl)) * DMODEL + c0 + dd;
      sk[tl][dd] = kb[g];
      sq[tl][dd] = qb[g];
      sv[tl][dd] = vb[g];
    }
    __syncthreads();

    for (int tl = 0; tl < 64; ++tl) {
      const int t = t0 + tl;
      if (tid < 64) {
        const int dd = tid;
        const float kr = sk[tl][dd];
        const float ek = expf(kr);
        zrun += ek;
        const float inv = 1.0f / zrun;
        float cs_, sn;
        fast_sincos((float)t * theta_v, &sn, &cs_);
        const float qv = sq[tl][dd];
        kh[dd] = ek * cs_;
        kh[64 + dd] = ek * sn;
        qph[dd] = qv * cs_ * inv;
        qph[64 + dd] = qv * sn * inv;
        vsh[dd] = sv[tl][dd];
      }
      __syncthreads();

      const float vj = vsh[lane];
      float accj = 0.f;
#pragma unroll
      for (int i = 0; i < 32; ++i) {
        T[i] = fmaf(kh[e0 + i], vj, T[i]);
        accj = fmaf(qph[e0 + i], T[i], accj);
      }
      opart[w][lane] = accj;
      __syncthreads();

      if (tid < 64) {
        const float o = opart[0][tid] + opart[1][tid] + opart[2][tid] + opart[3][tid];
        ob[((size_t)(b * NSEQ + t)) * DMODEL + c0 + tid] = o;
      }
    }
  }
}

// ---------------------------------------------------------------------------
// Gated group-RMSNorm, f32 (fallback path only).
// ---------------------------------------------------------------------------
__global__ __launch_bounds__(256) void gated_rmsnorm_f32(
    const float* __restrict__ o, const float* __restrict__ gate,
    const float* __restrict__ norm_w, float* __restrict__ outf) {
  const int gidx = blockIdx.x * 4 + (threadIdx.x >> 6);
  const int lane = threadIdx.x & 63;
  const size_t base = (size_t)gidx * 64 + lane;
  const float ov = o[base];
  const float gv = gate[base];
  const float g = ov / (1.f + expf(-gv));
  float ss = g * g;
#pragma unroll
  for (int off = 32; off; off >>= 1) ss += __shfl_xor(ss, off);
  const float rms = sqrtf(ss * (1.0f / 64.0f) + 1e-6f);
  const int cch = (gidx & 15) * 64 + lane;
  outf[base] = g / rms * norm_w[cch];
}

// ---------------------------------------------------------------------------
extern "C" void kernel_launch(void* const* d_in, const int* in_sizes, int n_in,
                              void* d_out, int out_size, void* d_ws, size_t ws_size,
                              hipStream_t stream) {
  const float* x      = (const float*)d_in[0];
  const float* wq     = (const float*)d_in[1];
  const float* wk     = (const float*)d_in[2];
  const float* wv     = (const float*)d_in[3];
  const float* wo     = (const float*)d_in[4];
  const float* wg1    = (const float*)d_in[5];
  const float* wg2    = (const float*)d_in[6];
  const float* norm_w = (const float*)d_in[7];
  float* out = (float*)d_out;

  const int M = BATCH * NSEQ;            // 4096
  const size_t SZ = (size_t)M * DMODEL;  // 4,194,304 elements
  const size_t WSZ = (size_t)DMODEL * DMODEL;  // 1M

  // fp32 region (regions sized f32; bf16 views alias the same memory)
  float* qbuf = (float*)d_ws;
  float* kbuf = qbuf + SZ;
  float* vbuf = kbuf + SZ;
  float* obuf = vbuf + SZ;
  float* gbuf = obuf + SZ;
  float* g1   = gbuf + SZ;                                  // M*64
  float* part = g1 + (size_t)M * HD;                        // 2*64*1024
  float* zoff = part + (size_t)BATCH * NCH * DMODEL;
  float* qpb  = zoff + (size_t)BATCH * NCH * DMODEL;
  float* Gb   = qpb + (size_t)BATCH * NH * NCH * CHUNK * 128;
  float* f32_end = Gb + (size_t)BATCH * NH * NCH * 8192;

  // bf16 region (ushort)
  unsigned short* xbf   = (unsigned short*)f32_end;
  unsigned short* wAll  = xbf + SZ;          // [wqT|wkT|wvT] 3072x1024
  unsigned short* wqT   = wAll;
  unsigned short* wkT   = wAll + WSZ;
  unsigned short* wvT   = wAll + 2 * WSZ;
  unsigned short* wg1T  = wAll + 3 * WSZ;            // 64x1024
  unsigned short* wg2T  = wg1T + (size_t)64 * DMODEL; // 1024x64
  unsigned short* g1b   = wg2T + (size_t)64 * DMODEL; // 4096x64
  unsigned short* woT   = wAll + 4 * WSZ;
  unsigned short* nrmbf = woT + WSZ;
  unsigned short* u16_end = nrmbf + SZ;

  const size_t need_full = (size_t)((char*)u16_end - (char*)d_ws);

  // bf16 views (full path)
  unsigned short* qbuf16 = (unsigned short*)qbuf;
  unsigned short* kbuf16 = (unsigned short*)kbuf;
  unsigned short* vbuf16 = (unsigned short*)vbuf;
  unsigned short* obuf16 = (unsigned short*)obuf;
  unsigned short* qpb16  = (unsigned short*)qpb;
  unsigned short* Gb16   = (unsigned short*)Gb;

  dim3 blk(256);
  dim3 grid_d((DMODEL + 127) / 128, (M + 127) / 128);
  dim3 grid_g1(1, (M + 127) / 128);

  const bool full_ok = ws_size >= need_full;

  if (full_ok) {
    // ONE batched kernel: 4 weight transposes + x conversion + wg1T + wg2T.
    transpose_cvt7<<<dim3(32, 32, 7), blk, 0, stream>>>(
        wq, wk, wv, wo, x, wg1, wg2, wqT, wkT, wvT, woT, xbf, wg1T, wg2T);
    // Low-rank gate step 1 only: g1 = x @ wg1 (N=64).  Step 2 (g1 @ wg2)
    // is fused into chunk_inter_norm (round-33).
    gemm_bf16_g1<<<dim3(M / 16), blk, 0, stream>>>(xbf, wg1T, g1b);
    // Fused projections: 4096x3072x1024, bf16 outputs, BM=128 -> 768 blocks.
    gemm_bf16_fused<<<dim3((M / 128) * (3 * DMODEL / 128)), blk, 0, stream>>>(
        xbf, wAll, qbuf16, kbuf16, vbuf16, M, 3 * DMODEL, DMODEL);

    chunk_partial<<<dim3(BATCH * NCH * 4), blk, 0, stream>>>(kbuf16, part);
    chunk_zoff<<<dim3(8), blk, 0, stream>>>(part, zoff);
    chunk_attn<<<dim3(BATCH * NH * NCH), blk, 0, stream>>>(qbuf16, kbuf16, vbuf16,
                                                           zoff, qpb16, Gb16, obuf16);
    chunk_prefix<<<dim3(BATCH * NH * 8192 / 512), blk, 0, stream>>>(Gb16);
    // Inter-chunk + gate MFMA + gated RMSNorm, all fused.
    chunk_inter_norm<<<dim3(BATCH * NH * NCH), blk, 0, stream>>>(
        qpb16, Gb16, obuf16, g1b, wg2T, norm_w, nrmbf);

    // wo GEMM: BM=32 -> 1024 blocks (4/CU).
    gemm_bf16_wo<<<dim3((M / 32) * (DMODEL / 128)), blk, 0, stream>>>(
        nrmbf, woT, out, M, DMODEL, DMODEL);
  } else {
    // f32 fallback: separate buffers, sequential scan.
    gemm_f32<1><<<grid_d, blk, 0, stream>>>(x, wq, qbuf, M, DMODEL, DMODEL);
    gemm_f32<0><<<grid_d, blk, 0, stream>>>(x, wk, kbuf, M, DMODEL, DMODEL);
    gemm_f32<0><<<grid_d, blk, 0, stream>>>(x, wv, vbuf, M, DMODEL, DMODEL);
    gemm_f32<0><<<grid_g1, blk, 0, stream>>>(x, wg1, g1, M, HD, DMODEL);
    gemm_f32<0><<<grid_d, blk, 0, stream>>>(g1, wg2, gbuf, M, DMODEL, HD);
    scan_kernel<<<dim3(BATCH * NH), blk, 0, stream>>>(qbuf, kbuf, vbuf, obuf);
    float* nrm = kbuf;
    gated_rmsnorm_f32<<<dim3(M * NH / 4), blk, 0, stream>>>(obuf, gbuf, norm_w, nrm);
    gemm_f32<0><<<grid_d, blk, 0, stream>>>(nrm, wo, out, M, DMODEL, DMODEL);
  }
}